// Round 19
// baseline (1619.190 us; speedup 1.0000x reference)
//
#include <hip/hip_runtime.h>

#define P 16384
#define NLAYERS 5
#define NND 98304          // P*(NLAYERS+1)
#define D 64
#define S 16
#define F 80               // D+S
#define KP1 96             // K of layer-1 GEMM padded to 32
#define H 256
#define EDG 262144         // 1<<18
#define NG 64
#define NSETS 13           // 5 inner + 4 fwd + 4 bwd
#define RSP 16385          // rowstart pitch (P+1)
#define LDP 40             // LDS K-stride for 32-chunks (80B rows, <=2-way aliasing)
#define LXS 100            // X-tile LDS row stride (96+4)

typedef __attribute__((ext_vector_type(8))) short s16x8;
typedef __attribute__((ext_vector_type(4))) float f32x4;

// ---------------------------------------------------------------- utilities
__device__ __forceinline__ void fatomic_add(float* p, float v) {
    unsafeAtomicAdd(p, v);
}
__device__ __forceinline__ unsigned short bf16_rne(float x) {
    unsigned int u = __float_as_uint(x);
    unsigned int r = u + 0x7fffu + ((u >> 16) & 1u);
    return (unsigned short)(r >> 16);
}
__device__ __forceinline__ float bf16_to_f(unsigned short b) {
    return __uint_as_float(((unsigned int)b) << 16);
}

// ---------------------------------------------------------------- init X + zero deg + zero PL
__global__ void k_init_x(const float* __restrict__ x0, float* __restrict__ X,
                         int* __restrict__ deg, float* __restrict__ PL) {
    int idx = blockIdx.x * blockDim.x + threadIdx.x;
    if (idx < NND * D) {
        int row = idx >> 6, f = idx & 63;
        X[idx] = (f == 0) ? x0[row] : 0.0f;
        return;
    }
    int r = idx - NND * D;
    if (r < NSETS * P) { deg[r] = 0; return; }
    r -= NSETS * P;
    if (r < NG * D) PL[r] = 0.0f;
}

// ---------------------------------------------------------------- weight transpose + split (all 3 layers)
__global__ void k_wsplit_all(const float* __restrict__ W1, const float* __restrict__ W2,
                             const float* __restrict__ W3,
                             unsigned short* __restrict__ w1h, unsigned short* __restrict__ w1l,
                             unsigned short* __restrict__ w2h, unsigned short* __restrict__ w2l,
                             unsigned short* __restrict__ w3h, unsigned short* __restrict__ w3l) {
    const int n1 = 4 * H * KP1, n2 = 4 * H * H, n3 = 4 * D * H;
    int idx = blockIdx.x * blockDim.x + threadIdx.x;
    const float* W; unsigned short *h, *l; int K, N, Kp, i;
    if (idx < n1)              { W = W1; h = w1h; l = w1l; K = F; N = H; Kp = KP1; i = idx; }
    else if (idx < n1 + n2)    { W = W2; h = w2h; l = w2l; K = H; N = H; Kp = H;   i = idx - n1; }
    else if (idx < n1 + n2 + n3){ W = W3; h = w3h; l = w3l; K = H; N = D; Kp = H;  i = idx - n1 - n2; }
    else return;
    int set = i / (N * Kp), rem = i - set * (N * Kp);
    int n = rem / Kp, kp = rem - n * Kp;
    float v = (kp < K) ? W[(size_t)set * K * N + (size_t)kp * N + n] : 0.0f;
    unsigned short hh = bf16_rne(v);
    h[i] = hh;
    l[i] = bf16_rne(v - bf16_to_f(hh));
}

// ---------------------------------------------------------------- CSR build (batched, 13 sets) — R15-proven
__device__ __forceinline__ const int* set_ptr(int t, const int* inner, const int* fwd,
                                              const int* bwd) {
    if (t < 5) return inner + (size_t)t * EDG;
    if (t < 9) return fwd + (size_t)(t - 5) * EDG;
    return bwd + (size_t)(t - 9) * EDG;
}

__global__ void k_csr_hist(const int* __restrict__ inner_dst, const int* __restrict__ fwd_dst,
                           const int* __restrict__ bwd_dst, int* __restrict__ deg,
                           int* __restrict__ rank) {
    int idx = blockIdx.x * blockDim.x + threadIdx.x;
    if (idx >= NSETS * EDG) return;
    int t = idx >> 18, e = idx & (EDG - 1);
    const int* dstp = set_ptr(t, inner_dst, fwd_dst, bwd_dst);
    rank[idx] = atomicAdd(&deg[t * P + dstp[e]], 1);
}

__global__ __launch_bounds__(1024) void k_csr_scan(const int* __restrict__ deg,
                                                   int* __restrict__ rowstart) {
    __shared__ int part[1024];
    int t = blockIdx.x;
    const int* d = deg + t * P;
    int* rs = rowstart + (size_t)t * RSP;
    int tid = threadIdx.x;
    int base = tid * 16;
    int loc[16], sum = 0;
#pragma unroll
    for (int i = 0; i < 16; ++i) { loc[i] = sum; sum += d[base + i]; }
    part[tid] = sum;
    __syncthreads();
    for (int off = 1; off < 1024; off <<= 1) {
        int v = (tid >= off) ? part[tid - off] : 0;
        __syncthreads();
        part[tid] += v;
        __syncthreads();
    }
    int pre = tid ? part[tid - 1] : 0;
#pragma unroll
    for (int i = 0; i < 16; ++i) rs[base + i] = pre + loc[i];
    if (tid == 1023) rs[P] = pre + sum;
}

__global__ void k_csr_scatter(const int* __restrict__ inner_src, const int* __restrict__ inner_dst,
                              const int* __restrict__ fwd_src, const int* __restrict__ fwd_dst,
                              const int* __restrict__ bwd_src, const int* __restrict__ bwd_dst,
                              const int* __restrict__ rowstart, const int* __restrict__ rank,
                              int* __restrict__ elist) {
    int idx = blockIdx.x * blockDim.x + threadIdx.x;
    if (idx >= NSETS * EDG) return;
    int t = idx >> 18, e = idx & (EDG - 1);
    const int* srcp = set_ptr(t, inner_src, fwd_src, bwd_src);
    const int* dstp = set_ptr(t, inner_dst, fwd_dst, bwd_dst);
    int dv = dstp[e];
    elist[(size_t)t * EDG + rowstart[(size_t)t * RSP + dv] + rank[idx]] = srcp[e];
}

// ---------------------------------------------------------------- gather conv input (wave per node) — proven
__global__ __launch_bounds__(256) void k_gather_T(const float* __restrict__ X,
                                                  const float* __restrict__ st,
                                                  const int* __restrict__ elist,
                                                  const int* __restrict__ rowstart,
                                                  unsigned short* __restrict__ Th,
                                                  unsigned short* __restrict__ Tl,
                                                  int dst_gbase, int src_gbase,
                                                  const float* __restrict__ eps, int ei) {
    int wv = threadIdx.x >> 6, l = threadIdx.x & 63;
    int v = blockIdx.x * 4 + wv;
    int beg = rowstart[v], end = rowstart[v + 1];
    float scale = 1.0f + eps[ei];
    int g = dst_gbase + v;
    float accX = X[(size_t)g * D + l] * scale;
    float accS = (l < S) ? st[(size_t)g * S + l] * scale : 0.0f;
    for (int i = beg; i < end; ++i) {
        int s = src_gbase + elist[i];            // wave-uniform load
        accX += X[(size_t)s * D + l];
        if (l < S) accS += st[(size_t)s * S + l];
    }
    unsigned short hx = bf16_rne(accX);
    Th[(size_t)v * KP1 + l] = hx;
    Tl[(size_t)v * KP1 + l] = bf16_rne(accX - bf16_to_f(hx));
    if (l < 32) {
        float vs = (l < S) ? accS : 0.0f;        // cols 80..95 = zero pad
        unsigned short hs = bf16_rne(vs);
        Th[(size_t)v * KP1 + D + l] = hs;
        Tl[(size_t)v * KP1 + D + l] = (l < S) ? bf16_rne(vs - bf16_to_f(hs)) : (unsigned short)0;
    }
}

// ---------------------------------------------------------------- GEMM1 (128x128, 8 waves, LDS) — R8-proven
template<bool CV>
__global__ __launch_bounds__(512) void k_gemm_big(
    const unsigned short* __restrict__ Ahp, const unsigned short* __restrict__ Alp, int lda,
    const float* __restrict__ Xsrc, const float* __restrict__ stsrc, int gbase,
    const unsigned short* __restrict__ Wh, const unsigned short* __restrict__ Wl, int Kp,
    const float* __restrict__ bias,
    unsigned short* __restrict__ Ch, unsigned short* __restrict__ Cl, int ldc)
{
    __shared__ unsigned short Ah[128][LDP], Al[128][LDP];
    __shared__ unsigned short Bh[128][LDP], Bl[128][LDP];   // 40 KB total

    int tid = threadIdx.x;
    int lane = tid & 63, wid = tid >> 6;       // 8 waves
    int wm = wid >> 2, wn = wid & 3;           // 2 x 4, wave tile 64x32
    int m0 = blockIdx.y * 128, n0 = blockIdx.x * 128;

    f32x4 acc[4][2] = {};

    int ar = tid >> 2;
    int ac = (tid & 3) * 8;
    int la = lane & 15, lg = lane >> 4;

    for (int k0 = 0; k0 < Kp; k0 += 32) {
        if (!CV) {
            size_t oa = (size_t)(m0 + ar) * lda + k0 + ac;
            *(s16x8*)&Ah[ar][ac] = *(const s16x8*)&Ahp[oa];
            *(s16x8*)&Al[ar][ac] = *(const s16x8*)&Alp[oa];
        } else {
            int g = gbase + m0 + ar;
            int k = k0 + ac;
            float vv[8];
            if (k < D) {
                float4 a = *(const float4*)&Xsrc[(size_t)g * D + k];
                float4 b = *(const float4*)&Xsrc[(size_t)g * D + k + 4];
                vv[0]=a.x; vv[1]=a.y; vv[2]=a.z; vv[3]=a.w;
                vv[4]=b.x; vv[5]=b.y; vv[6]=b.z; vv[7]=b.w;
            } else if (k < F) {
                float4 a = *(const float4*)&stsrc[(size_t)g * S + (k - D)];
                float4 b = *(const float4*)&stsrc[(size_t)g * S + (k - D) + 4];
                vv[0]=a.x; vv[1]=a.y; vv[2]=a.z; vv[3]=a.w;
                vv[4]=b.x; vv[5]=b.y; vv[6]=b.z; vv[7]=b.w;
            } else {
#pragma unroll
                for (int j = 0; j < 8; ++j) vv[j] = 0.0f;
            }
#pragma unroll
            for (int j = 0; j < 8; ++j) {
                unsigned short hh = bf16_rne(vv[j]);
                Ah[ar][ac + j] = hh;
                Al[ar][ac + j] = bf16_rne(vv[j] - bf16_to_f(hh));
            }
        }
        {
            size_t ob = (size_t)(n0 + ar) * Kp + k0 + ac;
            *(s16x8*)&Bh[ar][ac] = *(const s16x8*)&Wh[ob];
            *(s16x8*)&Bl[ar][ac] = *(const s16x8*)&Wl[ob];
        }
        __syncthreads();

        int kf = lg * 8;
        s16x8 ah[4], al[4], bh[2], bl[2];
#pragma unroll
        for (int m = 0; m < 4; ++m) {
            int r = wm * 64 + m * 16 + la;
            ah[m] = *(const s16x8*)&Ah[r][kf];
            al[m] = *(const s16x8*)&Al[r][kf];
        }
#pragma unroll
        for (int n = 0; n < 2; ++n) {
            int r = wn * 32 + n * 16 + la;
            bh[n] = *(const s16x8*)&Bh[r][kf];
            bl[n] = *(const s16x8*)&Bl[r][kf];
        }
#pragma unroll
        for (int m = 0; m < 4; ++m)
#pragma unroll
            for (int n = 0; n < 2; ++n) {
                acc[m][n] = __builtin_amdgcn_mfma_f32_16x16x32_bf16(ah[m], bh[n], acc[m][n], 0, 0, 0);
                acc[m][n] = __builtin_amdgcn_mfma_f32_16x16x32_bf16(ah[m], bl[n], acc[m][n], 0, 0, 0);
                acc[m][n] = __builtin_amdgcn_mfma_f32_16x16x32_bf16(al[m], bh[n], acc[m][n], 0, 0, 0);
            }
        __syncthreads();
    }

#pragma unroll
    for (int n = 0; n < 2; ++n) {
        int col = n0 + wn * 32 + n * 16 + la;
        float bv = bias[col];
#pragma unroll
        for (int m = 0; m < 4; ++m) {
            int row = m0 + wm * 64 + m * 16 + lg * 4;
#pragma unroll
            for (int r = 0; r < 4; ++r) {
                float v = fmaxf(acc[m][n][r] + bv, 0.0f);
                size_t o = (size_t)(row + r) * ldc + col;
                unsigned short hh = bf16_rne(v);
                Ch[o] = hh;
                Cl[o] = bf16_rne(v - bf16_to_f(hh));
            }
        }
    }
}

// ---------------------------------------------------------------- fused GEMM2+GEMM3 (+optional node GEMM1)
// 32-row tile, grid 512, 2 blocks/CU. H2 lives in REGISTERS (phase-1 acc); phase 2 redistributes it
// through a tiny double-buffered LDS slice: wave j's acc == H2 cols [j*32,+32) == phase-2 k-step j.
// MODE 0: phase3 writes X to global. MODE 1: X tile stays in LDS; phase4 = node_dnn GEMM1 -> H1.
template<int MODE>
__global__ __launch_bounds__(512, 4) void k_mlp23(
    const unsigned short* __restrict__ H1h, const unsigned short* __restrict__ H1l,
    const unsigned short* __restrict__ W2h, const unsigned short* __restrict__ W2l,
    const float* __restrict__ b2,
    const unsigned short* __restrict__ W3h, const unsigned short* __restrict__ W3l,
    const float* __restrict__ b3,
    float* __restrict__ Xout,
    const unsigned short* __restrict__ W1h3, const unsigned short* __restrict__ W1l3,
    const float* __restrict__ b13,
    unsigned short* __restrict__ H1oh, unsigned short* __restrict__ H1ol,
    int st_gbase, const float* __restrict__ stsrc)
{
    __shared__ unsigned short A1h[32][LDP], A1l[32][LDP];          // 5.1 KB
    __shared__ unsigned short B1h[256][LDP], B1l[256][LDP];        // 41 KB (W2 / W3 / W1_3)
    __shared__ unsigned short Hbh[2][32][LDP], Hbl[2][32][LDP];    // 10.2 KB (H2 k-slice dbuf)
    __shared__ unsigned short Xsh[(MODE == 1) ? 32 : 1][LXS];      // 6.4 KB (MODE 1)
    __shared__ unsigned short Xsl[(MODE == 1) ? 32 : 1][LXS];

    int tid = threadIdx.x;
    int lane = tid & 63, wid = tid >> 6;
    int la = lane & 15, lg = lane >> 4;
    int r0 = blockIdx.x * 32;

    // ================= phase 1: H2(regs) = H1 @ W2^T; wave wid owns cols [wid*32, +32)
    f32x4 acc[2][2] = {};
    for (int k0 = 0; k0 < H; k0 += 32) {
        if (tid < 256) {           // A: 32 rows x 4 chunks x 2 planes
            int pl = tid >> 7, rem = tid & 127;
            int ar = rem >> 2, aq = (rem & 3) * 8;
            const unsigned short* src = pl ? H1l : H1h;
            unsigned short (*dsth)[LDP] = pl ? A1l : A1h;
            *(s16x8*)&dsth[ar][aq] = *(const s16x8*)&src[(size_t)(r0 + ar) * H + k0 + aq];
        }
#pragma unroll
        for (int j = 0; j < 4; ++j) {   // B: W2 256 rows x 4 chunks x 2 planes
            int id = j * 512 + tid;
            int bpl = id >> 10, brem = id & 1023;
            int br = brem >> 2, bq = (brem & 3) * 8;
            const unsigned short* src = bpl ? W2l : W2h;
            unsigned short (*dsth)[LDP] = bpl ? B1l : B1h;
            *(s16x8*)&dsth[br][bq] = *(const s16x8*)&src[(size_t)br * H + k0 + bq];
        }
        __syncthreads();

        int kf = lg * 8;
        s16x8 ah[2], al[2], bh[2], bl[2];
#pragma unroll
        for (int m = 0; m < 2; ++m) {
            int r = m * 16 + la;
            ah[m] = *(const s16x8*)&A1h[r][kf];
            al[m] = *(const s16x8*)&A1l[r][kf];
        }
#pragma unroll
        for (int n = 0; n < 2; ++n) {
            int r = wid * 32 + n * 16 + la;
            bh[n] = *(const s16x8*)&B1h[r][kf];
            bl[n] = *(const s16x8*)&B1l[r][kf];
        }
#pragma unroll
        for (int m = 0; m < 2; ++m)
#pragma unroll
            for (int n = 0; n < 2; ++n) {
                acc[m][n] = __builtin_amdgcn_mfma_f32_16x16x32_bf16(ah[m], bh[n], acc[m][n], 0, 0, 0);
                acc[m][n] = __builtin_amdgcn_mfma_f32_16x16x32_bf16(ah[m], bl[n], acc[m][n], 0, 0, 0);
                acc[m][n] = __builtin_amdgcn_mfma_f32_16x16x32_bf16(al[m], bh[n], acc[m][n], 0, 0, 0);
            }
        __syncthreads();
    }

    // ================= phase 2: X(acc2) = relu(H2+b2) @ W3^T; H2 via Hbuf, k-step j fed by wave j
    int wm = wid >> 2, wn = wid & 3;
    f32x4 acc2 = {};
    {
        int pl = tid >> 8, rem = tid & 255;
        int br = rem >> 2, bq = (rem & 3) * 8;     // W3: 64 rows x 4 chunks x 2 planes
        for (int j = 0; j < 8; ++j) {
            int k0 = j * 32;
            {
                const unsigned short* src = pl ? W3l : W3h;
                unsigned short (*dsth)[LDP] = pl ? B1l : B1h;
                *(s16x8*)&dsth[br][bq] = *(const s16x8*)&src[(size_t)br * H + k0 + bq];
            }
            if (wid == j) {     // dump this wave's H2 slice (bias+relu+split)
#pragma unroll
                for (int n = 0; n < 2; ++n) {
                    int col = n * 16 + la;
                    float bv = b2[k0 + col];
#pragma unroll
                    for (int m = 0; m < 2; ++m) {
                        int row = m * 16 + lg * 4;
#pragma unroll
                        for (int r = 0; r < 4; ++r) {
                            float v = fmaxf(acc[m][n][r] + bv, 0.0f);
                            unsigned short hh = bf16_rne(v);
                            Hbh[j & 1][row + r][col] = hh;
                            Hbl[j & 1][row + r][col] = bf16_rne(v - bf16_to_f(hh));
                        }
                    }
                }
            }
            __syncthreads();

            int kf = lg * 8;
            s16x8 ah, al, bh, bl;
            {
                int r = wm * 16 + la;
                ah = *(const s16x8*)&Hbh[j & 1][r][kf];
                al = *(const s16x8*)&Hbl[j & 1][r][kf];
            }
            {
                int r = wn * 16 + la;
                bh = *(const s16x8*)&B1h[r][kf];
                bl = *(const s16x8*)&B1l[r][kf];
            }
            acc2 = __builtin_amdgcn_mfma_f32_16x16x32_bf16(ah, bh, acc2, 0, 0, 0);
            acc2 = __builtin_amdgcn_mfma_f32_16x16x32_bf16(ah, bl, acc2, 0, 0, 0);
            acc2 = __builtin_amdgcn_mfma_f32_16x16x32_bf16(al, bh, acc2, 0, 0, 0);
            __syncthreads();
        }
    }

    // ================= phase 3: write X (MODE 0) or stash X tile in LDS (MODE 1)
    {
        int col = wn * 16 + la;
        float bv = b3[col];
        int rloc = wm * 16 + lg * 4;
#pragma unroll
        for (int r = 0; r < 4; ++r) {
            float v = fmaxf(acc2[r] + bv, 0.0f);
            if (MODE == 0) {
                Xout[(size_t)(r0 + rloc + r) * D + col] = v;
            } else {
                unsigned short hh = bf16_rne(v);
                Xsh[rloc + r][col] = hh;
                Xsl[rloc + r][col] = bf16_rne(v - bf16_to_f(hh));
            }
        }
    }

    if (MODE == 1) {
        {   // static cols 64..79 + zero pad 80..95 (32 rows x 16, one elem/thread)
            int row = tid >> 4, c = tid & 15;
            int g = st_gbase + r0 + row;
            float sv = stsrc[(size_t)g * S + c];
            unsigned short h0 = bf16_rne(sv);
            Xsh[row][D + c] = h0;
            Xsl[row][D + c] = bf16_rne(sv - bf16_to_f(h0));
            Xsh[row][F + c] = 0; Xsl[row][F + c] = 0;
        }
        __syncthreads();

        // ================= phase 4: H1' = relu([X|st|0] @ W1_3^T + b1_3), 32x256, K=96
        f32x4 acc4[2][2] = {};
        for (int k0 = 0; k0 < KP1; k0 += 32) {
#pragma unroll
            for (int j = 0; j < 4; ++j) {
                int id = j * 512 + tid;
                int bpl = id >> 10, brem = id & 1023;
                int br = brem >> 2, bq = (brem & 3) * 8;
                const unsigned short* src = bpl ? W1l3 : W1h3;
                unsigned short (*dsth)[LDP] = bpl ? B1l : B1h;
                *(s16x8*)&dsth[br][bq] = *(const s16x8*)&src[(size_t)br * KP1 + k0 + bq];
            }
            __syncthreads();

            int kf = lg * 8;
            s16x8 ah[2], al[2], bh[2], bl[2];
#pragma unroll
            for (int m = 0; m < 2; ++m) {
                int r = m * 16 + la;
                ah[m] = *(const s16x8*)&Xsh[r][k0 + kf];
                al[m] = *(const s16x8*)&Xsl[r][k0 + kf];
            }
#pragma unroll
            for (int n = 0; n < 2; ++n) {
                int r = wid * 32 + n * 16 + la;
                bh[n] = *(const s16x8*)&B1h[r][kf];
                bl[n] = *(const s16x8*)&B1l[r][kf];
            }
#pragma unroll
            for (int m = 0; m < 2; ++m)
#pragma unroll
                for (int n = 0; n < 2; ++n) {
                    acc4[m][n] = __builtin_amdgcn_mfma_f32_16x16x32_bf16(ah[m], bh[n], acc4[m][n], 0, 0, 0);
                    acc4[m][n] = __builtin_amdgcn_mfma_f32_16x16x32_bf16(ah[m], bl[n], acc4[m][n], 0, 0, 0);
                    acc4[m][n] = __builtin_amdgcn_mfma_f32_16x16x32_bf16(al[m], bh[n], acc4[m][n], 0, 0, 0);
                }
            __syncthreads();
        }
#pragma unroll
        for (int n = 0; n < 2; ++n) {
            int col = wid * 32 + n * 16 + la;
            float bv = b13[col];
#pragma unroll
            for (int m = 0; m < 2; ++m) {
                int row = r0 + m * 16 + lg * 4;
#pragma unroll
                for (int r = 0; r < 4; ++r) {
                    float v = fmaxf(acc4[m][n][r] + bv, 0.0f);
                    size_t o = (size_t)(row + r) * H + col;
                    unsigned short hh = bf16_rne(v);
                    H1oh[o] = hh;
                    H1ol[o] = bf16_rne(v - bf16_to_f(hh));
                }
            }
        }
    }
}

// ---------------------------------------------------------------- two-stage pooling
#define PROWS 1024
__global__ __launch_bounds__(256) void k_pool2(const float* __restrict__ X,
                                               const int* __restrict__ bidx,
                                               float* __restrict__ PL) {
    __shared__ float lds[NG * D];
    int tid = threadIdx.x;
    for (int i = tid; i < NG * D; i += 256) lds[i] = 0.0f;
    __syncthreads();
    int base = blockIdx.x * PROWS;
    int f = tid & 63, rg = tid >> 6;
    for (int r = base + rg; r < base + PROWS; r += 4) {
        int g = bidx[r];
        atomicAdd(&lds[g * D + f], X[(size_t)r * D + f]);
    }
    __syncthreads();
    for (int i = tid; i < NG * D; i += 256) {
        float v = lds[i];
        if (v != 0.0f) fatomic_add(&PL[i], v);
    }
}

// ---------------------------------------------------------------- final linear head
__global__ void k_final(const float* __restrict__ pooled, const float* __restrict__ lin_w,
                        const float* __restrict__ lin_b, float* __restrict__ out) {
    int g = threadIdx.x;
    if (g >= NG) return;
    float acc = lin_b[0];
#pragma unroll
    for (int d2 = 0; d2 < D; ++d2) acc += pooled[g * D + d2] * lin_w[d2];
    out[g] = fmaxf(acc, 0.0f);
}

// ---------------------------------------------------------------- launch
extern "C" void kernel_launch(void* const* d_in, const int* in_sizes, int n_in,
                              void* d_out, int out_size, void* d_ws, size_t ws_size,
                              hipStream_t stream) {
    const float* x0    = (const float*)d_in[0];
    const float* stat  = (const float*)d_in[1];
    const float* W1    = (const float*)d_in[2];
    const float* b1    = (const float*)d_in[3];
    const float* W2    = (const float*)d_in[4];
    const float* b2    = (const float*)d_in[5];
    const float* W3    = (const float*)d_in[6];
    const float* b3    = (const float*)d_in[7];
    const float* eps   = (const float*)d_in[8];
    const float* lin_w = (const float*)d_in[9];
    const float* lin_b = (const float*)d_in[10];
    const int* inner_src = (const int*)d_in[11];
    const int* inner_dst = (const int*)d_in[12];
    const int* fwd_src   = (const int*)d_in[13];
    const int* fwd_dst   = (const int*)d_in[14];
    const int* bwd_src   = (const int*)d_in[15];
    const int* bwd_dst   = (const int*)d_in[16];
    const int* bidx      = (const int*)d_in[17];

    float* X  = (float*)d_ws;                                 // NND*64 f32
    float* PL = X + (size_t)NND * D;                          // NG*64 f32
    unsigned short* Th  = (unsigned short*)(PL + NG * D);     // [P][96]
    unsigned short* Tl  = Th  + (size_t)P * KP1;
    unsigned short* H1h = Tl  + (size_t)P * KP1;              // [P][256]
    unsigned short* H1l = H1h + (size_t)P * H;
    unsigned short* w1h = H1l + (size_t)P * H;                // [4][256][96]
    unsigned short* w1l = w1h + (size_t)4 * H * KP1;
    unsigned short* w2h = w1l + (size_t)4 * H * KP1;          // [4][256][256]
    unsigned short* w2l = w2h + (size_t)4 * H * H;
    unsigned short* w3h = w2l + (size_t)4 * H * H;            // [4][64][256]
    unsigned short* w3l = w3h + (size_t)4 * D * H;
    int* deg      = (int*)(w3l + (size_t)4 * D * H);          // NSETS*P
    int* rowstart = deg + (size_t)NSETS * P;                  // NSETS*RSP
    int* rank     = rowstart + (size_t)NSETS * RSP;           // NSETS*EDG
    int* elist    = rank + (size_t)NSETS * EDG;               // NSETS*EDG

    // ---- init X + zero deg/PL
    {
        int tot = NND * D + NSETS * P + NG * D;
        k_init_x<<<(tot + 255) / 256, 256, 0, stream>>>(x0, X, deg, PL);
    }
    // ---- weight prep
    {
        int tot = 4 * H * KP1 + 4 * H * H + 4 * D * H;
        k_wsplit_all<<<(tot + 255) / 256, 256, 0, stream>>>(W1, W2, W3, w1h, w1l, w2h, w2l, w3h, w3l);
    }
    // ---- CSR build (R15-proven 3-kernel pipeline)
    k_csr_hist<<<(NSETS * EDG) / 256, 256, 0, stream>>>(inner_dst, fwd_dst, bwd_dst, deg, rank);
    k_csr_scan<<<NSETS, 1024, 0, stream>>>(deg, rowstart);
    k_csr_scatter<<<(NSETS * EDG) / 256, 256, 0, stream>>>(inner_src, inner_dst, fwd_src, fwd_dst,
                                                           bwd_src, bwd_dst, rowstart, rank, elist);

    unsigned short* w13h = w1h + (size_t)3 * H * KP1;
    unsigned short* w13l = w1l + (size_t)3 * H * KP1;
    const float* b13 = b1 + 3 * H;

    auto mlp23_plain = [&](int set, int gbase_out) {
        k_mlp23<0><<<P / 32, 512, 0, stream>>>(
            H1h, H1l,
            w2h + (size_t)set * H * H, w2l + (size_t)set * H * H, b2 + set * H,
            w3h + (size_t)set * D * H, w3l + (size_t)set * D * H, b3 + set * D,
            X + (size_t)gbase_out * D,
            nullptr, nullptr, nullptr, nullptr, nullptr, 0, nullptr);
    };
    auto mlp23_fused = [&](int set, int gbase_node) {
        k_mlp23<1><<<P / 32, 512, 0, stream>>>(
            H1h, H1l,
            w2h + (size_t)set * H * H, w2l + (size_t)set * H * H, b2 + set * H,
            w3h + (size_t)set * D * H, w3l + (size_t)set * D * H, b3 + set * D,
            nullptr,
            w13h, w13l, b13, H1h, H1l, gbase_node, stat);
    };
    auto gemm1 = [&](int set) {
        k_gemm_big<false><<<dim3(H / 128, P / 128), 512, 0, stream>>>(
            Th, Tl, KP1, nullptr, nullptr, 0,
            w1h + (size_t)set * H * KP1, w1l + (size_t)set * H * KP1, KP1,
            b1 + set * H, H1h, H1l, H);
    };
    auto gather = [&](int t, int dst_gbase, int src_gbase, int ei) {
        k_gather_T<<<P / 4, 256, 0, stream>>>(
            X, stat, elist + (size_t)t * EDG, rowstart + (size_t)t * RSP,
            Th, Tl, dst_gbase, src_gbase, eps, ei);
    };

    // forward pass
    for (int il = 0; il < NLAYERS; ++il) {
        int s0 = il * P;
        gather(il, s0, s0, 0);
        gemm1(0);
        mlp23_plain(0, s0);
        if (il == NLAYERS - 1) continue;
        gather(5 + il, s0 + P, s0, 1);
        gemm1(1);
        mlp23_fused(1, s0 + P);
        mlp23_plain(3, s0 + P);
    }
    // backward pass
    for (int il = NLAYERS - 1; il >= 1; --il) {
        int s0 = (il - 1) * P;
        gather(9 + (il - 1), s0, s0 + P, 2);
        gemm1(2);
        mlp23_plain(2, s0);
        gather(il - 1, s0, s0, 0);
        gemm1(0);
        mlp23_fused(0, s0);
        mlp23_plain(3, s0);
    }

    k_pool2<<<NND / PROWS, 256, 0, stream>>>(X, bidx, PL);
    k_final<<<1, 64, 0, stream>>>(PL, lin_w, lin_b, (float*)d_out);
}

// Round 22
// 1212.264 us; speedup vs baseline: 1.3357x; 1.3357x over previous
//
#include <hip/hip_runtime.h>

#define P 16384
#define NLAYERS 5
#define NND 98304          // P*(NLAYERS+1)
#define D 64
#define S 16
#define F 80               // D+S
#define KP1 96             // K of layer-1 GEMM padded to 32
#define H 256
#define EDG 262144         // 1<<18
#define NG 64
#define NSETS 13           // 5 inner + 4 fwd + 4 bwd
#define RSP 16385          // rowstart pitch (P+1)
#define LDP 40             // LDS K-stride for 32-chunks (80B rows, <=2-way aliasing)
#define LH2 264            // H2 LDS row stride (256+8)
#define LXS 100            // X-tile LDS row stride (96+4)

typedef __attribute__((ext_vector_type(8))) short s16x8;
typedef __attribute__((ext_vector_type(4))) float f32x4;

// ---------------------------------------------------------------- utilities
__device__ __forceinline__ void fatomic_add(float* p, float v) {
    unsafeAtomicAdd(p, v);
}
__device__ __forceinline__ unsigned short bf16_rne(float x) {
    unsigned int u = __float_as_uint(x);
    unsigned int r = u + 0x7fffu + ((u >> 16) & 1u);
    return (unsigned short)(r >> 16);
}
__device__ __forceinline__ float bf16_to_f(unsigned short b) {
    return __uint_as_float(((unsigned int)b) << 16);
}

// ---------------------------------------------------------------- init X + zero deg + zero PL
__global__ void k_init_x(const float* __restrict__ x0, float* __restrict__ X,
                         int* __restrict__ deg, float* __restrict__ PL) {
    int idx = blockIdx.x * blockDim.x + threadIdx.x;
    if (idx < NND * D) {
        int row = idx >> 6, f = idx & 63;
        X[idx] = (f == 0) ? x0[row] : 0.0f;
        return;
    }
    int r = idx - NND * D;
    if (r < NSETS * P) { deg[r] = 0; return; }
    r -= NSETS * P;
    if (r < NG * D) PL[r] = 0.0f;
}

// ---------------------------------------------------------------- weight transpose + split (all 3 layers)
__global__ void k_wsplit_all(const float* __restrict__ W1, const float* __restrict__ W2,
                             const float* __restrict__ W3,
                             unsigned short* __restrict__ w1h, unsigned short* __restrict__ w1l,
                             unsigned short* __restrict__ w2h, unsigned short* __restrict__ w2l,
                             unsigned short* __restrict__ w3h, unsigned short* __restrict__ w3l) {
    const int n1 = 4 * H * KP1, n2 = 4 * H * H, n3 = 4 * D * H;
    int idx = blockIdx.x * blockDim.x + threadIdx.x;
    const float* W; unsigned short *h, *l; int K, N, Kp, i;
    if (idx < n1)              { W = W1; h = w1h; l = w1l; K = F; N = H; Kp = KP1; i = idx; }
    else if (idx < n1 + n2)    { W = W2; h = w2h; l = w2l; K = H; N = H; Kp = H;   i = idx - n1; }
    else if (idx < n1 + n2 + n3){ W = W3; h = w3h; l = w3l; K = H; N = D; Kp = H;  i = idx - n1 - n2; }
    else return;
    int set = i / (N * Kp), rem = i - set * (N * Kp);
    int n = rem / Kp, kp = rem - n * Kp;
    float v = (kp < K) ? W[(size_t)set * K * N + (size_t)kp * N + n] : 0.0f;
    unsigned short hh = bf16_rne(v);
    h[i] = hh;
    l[i] = bf16_rne(v - bf16_to_f(hh));
}

// ---------------------------------------------------------------- CSR build (batched, 13 sets) — R15-proven
__device__ __forceinline__ const int* set_ptr(int t, const int* inner, const int* fwd,
                                              const int* bwd) {
    if (t < 5) return inner + (size_t)t * EDG;
    if (t < 9) return fwd + (size_t)(t - 5) * EDG;
    return bwd + (size_t)(t - 9) * EDG;
}

__global__ void k_csr_hist(const int* __restrict__ inner_dst, const int* __restrict__ fwd_dst,
                           const int* __restrict__ bwd_dst, int* __restrict__ deg,
                           int* __restrict__ rank) {
    int idx = blockIdx.x * blockDim.x + threadIdx.x;
    if (idx >= NSETS * EDG) return;
    int t = idx >> 18, e = idx & (EDG - 1);
    const int* dstp = set_ptr(t, inner_dst, fwd_dst, bwd_dst);
    rank[idx] = atomicAdd(&deg[t * P + dstp[e]], 1);
}

__global__ __launch_bounds__(1024) void k_csr_scan(const int* __restrict__ deg,
                                                   int* __restrict__ rowstart) {
    __shared__ int part[1024];
    int t = blockIdx.x;
    const int* d = deg + t * P;
    int* rs = rowstart + (size_t)t * RSP;
    int tid = threadIdx.x;
    int base = tid * 16;
    int loc[16], sum = 0;
#pragma unroll
    for (int i = 0; i < 16; ++i) { loc[i] = sum; sum += d[base + i]; }
    part[tid] = sum;
    __syncthreads();
    for (int off = 1; off < 1024; off <<= 1) {
        int v = (tid >= off) ? part[tid - off] : 0;
        __syncthreads();
        part[tid] += v;
        __syncthreads();
    }
    int pre = tid ? part[tid - 1] : 0;
#pragma unroll
    for (int i = 0; i < 16; ++i) rs[base + i] = pre + loc[i];
    if (tid == 1023) rs[P] = pre + sum;
}

__global__ void k_csr_scatter(const int* __restrict__ inner_src, const int* __restrict__ inner_dst,
                              const int* __restrict__ fwd_src, const int* __restrict__ fwd_dst,
                              const int* __restrict__ bwd_src, const int* __restrict__ bwd_dst,
                              const int* __restrict__ rowstart, const int* __restrict__ rank,
                              int* __restrict__ elist) {
    int idx = blockIdx.x * blockDim.x + threadIdx.x;
    if (idx >= NSETS * EDG) return;
    int t = idx >> 18, e = idx & (EDG - 1);
    const int* srcp = set_ptr(t, inner_src, fwd_src, bwd_src);
    const int* dstp = set_ptr(t, inner_dst, fwd_dst, bwd_dst);
    int dv = dstp[e];
    elist[(size_t)t * EDG + rowstart[(size_t)t * RSP + dv] + rank[idx]] = srcp[e];
}

// ---------------------------------------------------------------- gather conv input (wave per node, 4-row ILP)
// lane l: row-group rg=l>>4, feature-chunk c=l&15. Each iteration consumes 4 source rows:
// one float4 X load (4 full rows across the wave) + one 4B static load. Cross-group merge
// via shfl_xor(16,32); lanes 0..15 add scaled self-term and write T (split bf16).
__global__ __launch_bounds__(256) void k_gather_T(const float* __restrict__ X,
                                                  const float* __restrict__ st,
                                                  const int* __restrict__ elist,
                                                  const int* __restrict__ rowstart,
                                                  unsigned short* __restrict__ Th,
                                                  unsigned short* __restrict__ Tl,
                                                  int dst_gbase, int src_gbase,
                                                  const float* __restrict__ eps, int ei) {
    int wv = threadIdx.x >> 6, l = threadIdx.x & 63;
    int v = blockIdx.x * 4 + wv;
    int beg = rowstart[v], end = rowstart[v + 1];
    float scale = 1.0f + eps[ei];
    int rg = l >> 4, c = l & 15;
    float ax0 = 0.f, ax1 = 0.f, ax2 = 0.f, ax3 = 0.f, as = 0.f;
    int i = beg;
    for (; i + 4 <= end; i += 4) {
        int s = src_gbase + elist[i + rg];
        float4 xv = *(const float4*)&X[(size_t)s * D + 4 * c];
        ax0 += xv.x; ax1 += xv.y; ax2 += xv.z; ax3 += xv.w;
        as += st[(size_t)s * S + c];
    }
    if (i < end) {
        int rem = end - i;
        if (rg < rem) {
            int s = src_gbase + elist[i + rg];
            float4 xv = *(const float4*)&X[(size_t)s * D + 4 * c];
            ax0 += xv.x; ax1 += xv.y; ax2 += xv.z; ax3 += xv.w;
            as += st[(size_t)s * S + c];
        }
    }
    // merge the 4 row-groups (butterfly over lane strides 16, 32)
#pragma unroll
    for (int off = 16; off < 64; off <<= 1) {
        ax0 += __shfl_xor(ax0, off, 64);
        ax1 += __shfl_xor(ax1, off, 64);
        ax2 += __shfl_xor(ax2, off, 64);
        ax3 += __shfl_xor(ax3, off, 64);
        as  += __shfl_xor(as,  off, 64);
    }
    if (l < 16) {
        int g = dst_gbase + v;
        float4 sx = *(const float4*)&X[(size_t)g * D + 4 * l];
        float f0 = ax0 + scale * sx.x;
        float f1 = ax1 + scale * sx.y;
        float f2 = ax2 + scale * sx.z;
        float f3 = ax3 + scale * sx.w;
        float fs = as + scale * st[(size_t)g * S + l];
        ushort4 hh, ll;
        hh.x = bf16_rne(f0); ll.x = bf16_rne(f0 - bf16_to_f(hh.x));
        hh.y = bf16_rne(f1); ll.y = bf16_rne(f1 - bf16_to_f(hh.y));
        hh.z = bf16_rne(f2); ll.z = bf16_rne(f2 - bf16_to_f(hh.z));
        hh.w = bf16_rne(f3); ll.w = bf16_rne(f3 - bf16_to_f(hh.w));
        *(ushort4*)&Th[(size_t)v * KP1 + 4 * l] = hh;
        *(ushort4*)&Tl[(size_t)v * KP1 + 4 * l] = ll;
        unsigned short hs = bf16_rne(fs);
        Th[(size_t)v * KP1 + D + l] = hs;
        Tl[(size_t)v * KP1 + D + l] = bf16_rne(fs - bf16_to_f(hs));
        Th[(size_t)v * KP1 + F + l] = 0;    // pad cols 80..95
        Tl[(size_t)v * KP1 + F + l] = 0;
    }
}

// ---------------------------------------------------------------- GEMM1 (128x128, 8 waves, LDS) — R8-proven
template<bool CV>
__global__ __launch_bounds__(512) void k_gemm_big(
    const unsigned short* __restrict__ Ahp, const unsigned short* __restrict__ Alp, int lda,
    const float* __restrict__ Xsrc, const float* __restrict__ stsrc, int gbase,
    const unsigned short* __restrict__ Wh, const unsigned short* __restrict__ Wl, int Kp,
    const float* __restrict__ bias,
    unsigned short* __restrict__ Ch, unsigned short* __restrict__ Cl, int ldc)
{
    __shared__ unsigned short Ah[128][LDP], Al[128][LDP];
    __shared__ unsigned short Bh[128][LDP], Bl[128][LDP];   // 40 KB total

    int tid = threadIdx.x;
    int lane = tid & 63, wid = tid >> 6;       // 8 waves
    int wm = wid >> 2, wn = wid & 3;           // 2 x 4, wave tile 64x32
    int m0 = blockIdx.y * 128, n0 = blockIdx.x * 128;

    f32x4 acc[4][2] = {};

    int ar = tid >> 2;
    int ac = (tid & 3) * 8;
    int la = lane & 15, lg = lane >> 4;

    for (int k0 = 0; k0 < Kp; k0 += 32) {
        if (!CV) {
            size_t oa = (size_t)(m0 + ar) * lda + k0 + ac;
            *(s16x8*)&Ah[ar][ac] = *(const s16x8*)&Ahp[oa];
            *(s16x8*)&Al[ar][ac] = *(const s16x8*)&Alp[oa];
        } else {
            int g = gbase + m0 + ar;
            int k = k0 + ac;
            float vv[8];
            if (k < D) {
                float4 a = *(const float4*)&Xsrc[(size_t)g * D + k];
                float4 b = *(const float4*)&Xsrc[(size_t)g * D + k + 4];
                vv[0]=a.x; vv[1]=a.y; vv[2]=a.z; vv[3]=a.w;
                vv[4]=b.x; vv[5]=b.y; vv[6]=b.z; vv[7]=b.w;
            } else if (k < F) {
                float4 a = *(const float4*)&stsrc[(size_t)g * S + (k - D)];
                float4 b = *(const float4*)&stsrc[(size_t)g * S + (k - D) + 4];
                vv[0]=a.x; vv[1]=a.y; vv[2]=a.z; vv[3]=a.w;
                vv[4]=b.x; vv[5]=b.y; vv[6]=b.z; vv[7]=b.w;
            } else {
#pragma unroll
                for (int j = 0; j < 8; ++j) vv[j] = 0.0f;
            }
#pragma unroll
            for (int j = 0; j < 8; ++j) {
                unsigned short hh = bf16_rne(vv[j]);
                Ah[ar][ac + j] = hh;
                Al[ar][ac + j] = bf16_rne(vv[j] - bf16_to_f(hh));
            }
        }
        {
            size_t ob = (size_t)(n0 + ar) * Kp + k0 + ac;
            *(s16x8*)&Bh[ar][ac] = *(const s16x8*)&Wh[ob];
            *(s16x8*)&Bl[ar][ac] = *(const s16x8*)&Wl[ob];
        }
        __syncthreads();

        int kf = lg * 8;
        s16x8 ah[4], al[4], bh[2], bl[2];
#pragma unroll
        for (int m = 0; m < 4; ++m) {
            int r = wm * 64 + m * 16 + la;
            ah[m] = *(const s16x8*)&Ah[r][kf];
            al[m] = *(const s16x8*)&Al[r][kf];
        }
#pragma unroll
        for (int n = 0; n < 2; ++n) {
            int r = wn * 32 + n * 16 + la;
            bh[n] = *(const s16x8*)&Bh[r][kf];
            bl[n] = *(const s16x8*)&Bl[r][kf];
        }
#pragma unroll
        for (int m = 0; m < 4; ++m)
#pragma unroll
            for (int n = 0; n < 2; ++n) {
                acc[m][n] = __builtin_amdgcn_mfma_f32_16x16x32_bf16(ah[m], bh[n], acc[m][n], 0, 0, 0);
                acc[m][n] = __builtin_amdgcn_mfma_f32_16x16x32_bf16(ah[m], bl[n], acc[m][n], 0, 0, 0);
                acc[m][n] = __builtin_amdgcn_mfma_f32_16x16x32_bf16(al[m], bh[n], acc[m][n], 0, 0, 0);
            }
        __syncthreads();
    }

#pragma unroll
    for (int n = 0; n < 2; ++n) {
        int col = n0 + wn * 32 + n * 16 + la;
        float bv = bias[col];
#pragma unroll
        for (int m = 0; m < 4; ++m) {
            int row = m0 + wm * 64 + m * 16 + lg * 4;
#pragma unroll
            for (int r = 0; r < 4; ++r) {
                float v = fmaxf(acc[m][n][r] + bv, 0.0f);
                size_t o = (size_t)(row + r) * ldc + col;
                unsigned short hh = bf16_rne(v);
                Ch[o] = hh;
                Cl[o] = bf16_rne(v - bf16_to_f(hh));
            }
        }
    }
}

// ---------------------------------------------------------------- fused GEMM2+GEMM3 (+optional node GEMM1), 64-row tile — R15-proven
// MODE 0: phase3 writes X to global. MODE 1: X tile stays in LDS; phase4 = node_dnn GEMM1 -> H1.
template<int MODE>
__global__ __launch_bounds__(512) void k_mlp23(
    const unsigned short* __restrict__ H1h, const unsigned short* __restrict__ H1l,
    const unsigned short* __restrict__ W2h, const unsigned short* __restrict__ W2l,
    const float* __restrict__ b2,
    const unsigned short* __restrict__ W3h, const unsigned short* __restrict__ W3l,
    const float* __restrict__ b3,
    float* __restrict__ Xout,
    const unsigned short* __restrict__ W1h3, const unsigned short* __restrict__ W1l3,
    const float* __restrict__ b13,
    unsigned short* __restrict__ H1oh, unsigned short* __restrict__ H1ol,
    int st_gbase, const float* __restrict__ stsrc)
{
    __shared__ unsigned short A1h[64][LDP], A1l[64][LDP];      // 10.2 KB
    __shared__ unsigned short B1h[256][LDP], B1l[256][LDP];    // 41 KB (reused for W3 / W1_3)
    __shared__ unsigned short H2hs[64][LH2], H2ls[64][LH2];    // 67.6 KB
    __shared__ unsigned short Xsh[64][LXS], Xsl[64][LXS];      // 25.6 KB (MODE 1)

    int tid = threadIdx.x;
    int lane = tid & 63, wid = tid >> 6;
    int la = lane & 15, lg = lane >> 4;
    int r0 = blockIdx.x * 64;

    // ================= phase 1: H2 = relu(H1 @ W2^T + b2), 64x256
    f32x4 acc[4][2] = {};
    {
        int apl = tid >> 8, arem = tid & 255;
        int ar = arem >> 2, aq = (arem & 3) * 8;
        for (int k0 = 0; k0 < H; k0 += 32) {
            {
                const unsigned short* src = apl ? H1l : H1h;
                unsigned short (*dsth)[LDP] = apl ? A1l : A1h;
                *(s16x8*)&dsth[ar][aq] = *(const s16x8*)&src[(size_t)(r0 + ar) * H + k0 + aq];
            }
#pragma unroll
            for (int j = 0; j < 4; ++j) {
                int id = j * 512 + tid;
                int bpl = id >> 10, brem = id & 1023;
                int br = brem >> 2, bq = (brem & 3) * 8;
                const unsigned short* src = bpl ? W2l : W2h;
                unsigned short (*dsth)[LDP] = bpl ? B1l : B1h;
                *(s16x8*)&dsth[br][bq] = *(const s16x8*)&src[(size_t)br * H + k0 + bq];
            }
            __syncthreads();

            int kf = lg * 8;
            s16x8 ah[4], al[4], bh[2], bl[2];
#pragma unroll
            for (int m = 0; m < 4; ++m) {
                int r = m * 16 + la;
                ah[m] = *(const s16x8*)&A1h[r][kf];
                al[m] = *(const s16x8*)&A1l[r][kf];
            }
#pragma unroll
            for (int n = 0; n < 2; ++n) {
                int r = wid * 32 + n * 16 + la;
                bh[n] = *(const s16x8*)&B1h[r][kf];
                bl[n] = *(const s16x8*)&B1l[r][kf];
            }
#pragma unroll
            for (int m = 0; m < 4; ++m)
#pragma unroll
                for (int n = 0; n < 2; ++n) {
                    acc[m][n] = __builtin_amdgcn_mfma_f32_16x16x32_bf16(ah[m], bh[n], acc[m][n], 0, 0, 0);
                    acc[m][n] = __builtin_amdgcn_mfma_f32_16x16x32_bf16(ah[m], bl[n], acc[m][n], 0, 0, 0);
                    acc[m][n] = __builtin_amdgcn_mfma_f32_16x16x32_bf16(al[m], bh[n], acc[m][n], 0, 0, 0);
                }
            __syncthreads();
        }
    }
#pragma unroll
    for (int n = 0; n < 2; ++n) {
        int col = wid * 32 + n * 16 + la;
        float bv = b2[col];
#pragma unroll
        for (int m = 0; m < 4; ++m) {
            int row = m * 16 + lg * 4;
#pragma unroll
            for (int r = 0; r < 4; ++r) {
                float v = fmaxf(acc[m][n][r] + bv, 0.0f);
                unsigned short hh = bf16_rne(v);
                H2hs[row + r][col] = hh;
                H2ls[row + r][col] = bf16_rne(v - bf16_to_f(hh));
            }
        }
    }
    __syncthreads();

    // ================= phase 2: Xtile = relu(H2 @ W3^T + b3), K=256
    int wm = wid >> 2, wn = wid & 3;
    f32x4 acc2[2] = {};
    {
        int apl = tid >> 8, arem = tid & 255;
        int br = arem >> 2, bq = (arem & 3) * 8;
        for (int k0 = 0; k0 < H; k0 += 32) {
            {
                const unsigned short* src = apl ? W3l : W3h;
                unsigned short (*dsth)[LDP] = apl ? B1l : B1h;
                *(s16x8*)&dsth[br][bq] = *(const s16x8*)&src[(size_t)br * H + k0 + bq];
            }
            __syncthreads();

            int kf = lg * 8;
            s16x8 ah[2], al[2], bh, bl;
#pragma unroll
            for (int m = 0; m < 2; ++m) {
                int r = wm * 32 + m * 16 + la;
                ah[m] = *(const s16x8*)&H2hs[r][k0 + kf];
                al[m] = *(const s16x8*)&H2ls[r][k0 + kf];
            }
            {
                int r = wn * 16 + la;
                bh = *(const s16x8*)&B1h[r][kf];
                bl = *(const s16x8*)&B1l[r][kf];
            }
#pragma unroll
            for (int m = 0; m < 2; ++m) {
                acc2[m] = __builtin_amdgcn_mfma_f32_16x16x32_bf16(ah[m], bh, acc2[m], 0, 0, 0);
                acc2[m] = __builtin_amdgcn_mfma_f32_16x16x32_bf16(ah[m], bl, acc2[m], 0, 0, 0);
                acc2[m] = __builtin_amdgcn_mfma_f32_16x16x32_bf16(al[m], bh, acc2[m], 0, 0, 0);
            }
            __syncthreads();
        }
    }
    {
        int col = wn * 16 + la;
        float bv = b3[col];
#pragma unroll
        for (int m = 0; m < 2; ++m) {
            int rloc = wm * 32 + m * 16 + lg * 4;
#pragma unroll
            for (int r = 0; r < 4; ++r) {
                float v = fmaxf(acc2[m][r] + bv, 0.0f);
                if (MODE == 0) {
                    Xout[(size_t)(r0 + rloc + r) * D + col] = v;
                } else {
                    unsigned short hh = bf16_rne(v);
                    Xsh[rloc + r][col] = hh;
                    Xsl[rloc + r][col] = bf16_rne(v - bf16_to_f(hh));
                }
            }
        }
    }

    if (MODE == 1) {
        {
            int row = tid >> 3, c2 = (tid & 7) * 2;
            int g = st_gbase + r0 + row;
            float2 sv = *(const float2*)&stsrc[(size_t)g * S + c2];
            unsigned short h0 = bf16_rne(sv.x);
            Xsh[row][D + c2] = h0;
            Xsl[row][D + c2] = bf16_rne(sv.x - bf16_to_f(h0));
            unsigned short h1b = bf16_rne(sv.y);
            Xsh[row][D + c2 + 1] = h1b;
            Xsl[row][D + c2 + 1] = bf16_rne(sv.y - bf16_to_f(h1b));
            Xsh[row][F + c2] = 0; Xsl[row][F + c2] = 0;
            Xsh[row][F + c2 + 1] = 0; Xsl[row][F + c2 + 1] = 0;
        }
        __syncthreads();

        // phase 4: H1' = relu([X|st|0] @ W1_3^T + b1_3), 64x256, K=96
        f32x4 acc4[4][2] = {};
        for (int k0 = 0; k0 < KP1; k0 += 32) {
#pragma unroll
            for (int j = 0; j < 4; ++j) {
                int id = j * 512 + tid;
                int bpl = id >> 10, brem = id & 1023;
                int br = brem >> 2, bq = (brem & 3) * 8;
                const unsigned short* src = bpl ? W1l3 : W1h3;
                unsigned short (*dsth)[LDP] = bpl ? B1l : B1h;
                *(s16x8*)&dsth[br][bq] = *(const s16x8*)&src[(size_t)br * KP1 + k0 + bq];
            }
            __syncthreads();

            int kf = lg * 8;
            s16x8 ah[4], al[4], bh[2], bl[2];
#pragma unroll
            for (int m = 0; m < 4; ++m) {
                int r = m * 16 + la;
                ah[m] = *(const s16x8*)&Xsh[r][k0 + kf];
                al[m] = *(const s16x8*)&Xsl[r][k0 + kf];
            }
#pragma unroll
            for (int n = 0; n < 2; ++n) {
                int r = wid * 32 + n * 16 + la;
                bh[n] = *(const s16x8*)&B1h[r][kf];
                bl[n] = *(const s16x8*)&B1l[r][kf];
            }
#pragma unroll
            for (int m = 0; m < 4; ++m)
#pragma unroll
                for (int n = 0; n < 2; ++n) {
                    acc4[m][n] = __builtin_amdgcn_mfma_f32_16x16x32_bf16(ah[m], bh[n], acc4[m][n], 0, 0, 0);
                    acc4[m][n] = __builtin_amdgcn_mfma_f32_16x16x32_bf16(ah[m], bl[n], acc4[m][n], 0, 0, 0);
                    acc4[m][n] = __builtin_amdgcn_mfma_f32_16x16x32_bf16(al[m], bh[n], acc4[m][n], 0, 0, 0);
                }
            __syncthreads();
        }
#pragma unroll
        for (int n = 0; n < 2; ++n) {
            int col = wid * 32 + n * 16 + la;
            float bv = b13[col];
#pragma unroll
            for (int m = 0; m < 4; ++m) {
                int row = r0 + m * 16 + lg * 4;
#pragma unroll
                for (int r = 0; r < 4; ++r) {
                    float v = fmaxf(acc4[m][n][r] + bv, 0.0f);
                    size_t o = (size_t)(row + r) * H + col;
                    unsigned short hh = bf16_rne(v);
                    H1oh[o] = hh;
                    H1ol[o] = bf16_rne(v - bf16_to_f(hh));
                }
            }
        }
    }
}

// ---------------------------------------------------------------- two-stage pooling
#define PROWS 1024
__global__ __launch_bounds__(256) void k_pool2(const float* __restrict__ X,
                                               const int* __restrict__ bidx,
                                               float* __restrict__ PL) {
    __shared__ float lds[NG * D];
    int tid = threadIdx.x;
    for (int i = tid; i < NG * D; i += 256) lds[i] = 0.0f;
    __syncthreads();
    int base = blockIdx.x * PROWS;
    int f = tid & 63, rg = tid >> 6;
    for (int r = base + rg; r < base + PROWS; r += 4) {
        int g = bidx[r];
        atomicAdd(&lds[g * D + f], X[(size_t)r * D + f]);
    }
    __syncthreads();
    for (int i = tid; i < NG * D; i += 256) {
        float v = lds[i];
        if (v != 0.0f) fatomic_add(&PL[i], v);
    }
}

// ---------------------------------------------------------------- final linear head
__global__ void k_final(const float* __restrict__ pooled, const float* __restrict__ lin_w,
                        const float* __restrict__ lin_b, float* __restrict__ out) {
    int g = threadIdx.x;
    if (g >= NG) return;
    float acc = lin_b[0];
#pragma unroll
    for (int d2 = 0; d2 < D; ++d2) acc += pooled[g * D + d2] * lin_w[d2];
    out[g] = fmaxf(acc, 0.0f);
}

// ---------------------------------------------------------------- launch
extern "C" void kernel_launch(void* const* d_in, const int* in_sizes, int n_in,
                              void* d_out, int out_size, void* d_ws, size_t ws_size,
                              hipStream_t stream) {
    const float* x0    = (const float*)d_in[0];
    const float* stat  = (const float*)d_in[1];
    const float* W1    = (const float*)d_in[2];
    const float* b1    = (const float*)d_in[3];
    const float* W2    = (const float*)d_in[4];
    const float* b2    = (const float*)d_in[5];
    const float* W3    = (const float*)d_in[6];
    const float* b3    = (const float*)d_in[7];
    const float* eps   = (const float*)d_in[8];
    const float* lin_w = (const float*)d_in[9];
    const float* lin_b = (const float*)d_in[10];
    const int* inner_src = (const int*)d_in[11];
    const int* inner_dst = (const int*)d_in[12];
    const int* fwd_src   = (const int*)d_in[13];
    const int* fwd_dst   = (const int*)d_in[14];
    const int* bwd_src   = (const int*)d_in[15];
    const int* bwd_dst   = (const int*)d_in[16];
    const int* bidx      = (const int*)d_in[17];

    float* X  = (float*)d_ws;                                 // NND*64 f32
    float* PL = X + (size_t)NND * D;                          // NG*64 f32
    unsigned short* Th  = (unsigned short*)(PL + NG * D);     // [P][96]
    unsigned short* Tl  = Th  + (size_t)P * KP1;
    unsigned short* H1h = Tl  + (size_t)P * KP1;              // [P][256]
    unsigned short* H1l = H1h + (size_t)P * H;
    unsigned short* w1h = H1l + (size_t)P * H;                // [4][256][96]
    unsigned short* w1l = w1h + (size_t)4 * H * KP1;
    unsigned short* w2h = w1l + (size_t)4 * H * KP1;          // [4][256][256]
    unsigned short* w2l = w2h + (size_t)4 * H * H;
    unsigned short* w3h = w2l + (size_t)4 * H * H;            // [4][64][256]
    unsigned short* w3l = w3h + (size_t)4 * D * H;
    int* deg      = (int*)(w3l + (size_t)4 * D * H);          // NSETS*P
    int* rowstart = deg + (size_t)NSETS * P;                  // NSETS*RSP
    int* rank     = rowstart + (size_t)NSETS * RSP;           // NSETS*EDG
    int* elist    = rank + (size_t)NSETS * EDG;               // NSETS*EDG

    // ---- init X + zero deg/PL
    {
        int tot = NND * D + NSETS * P + NG * D;
        k_init_x<<<(tot + 255) / 256, 256, 0, stream>>>(x0, X, deg, PL);
    }
    // ---- weight prep
    {
        int tot = 4 * H * KP1 + 4 * H * H + 4 * D * H;
        k_wsplit_all<<<(tot + 255) / 256, 256, 0, stream>>>(W1, W2, W3, w1h, w1l, w2h, w2l, w3h, w3l);
    }
    // ---- CSR build (R15-proven 3-kernel pipeline)
    k_csr_hist<<<(NSETS * EDG) / 256, 256, 0, stream>>>(inner_dst, fwd_dst, bwd_dst, deg, rank);
    k_csr_scan<<<NSETS, 1024, 0, stream>>>(deg, rowstart);
    k_csr_scatter<<<(NSETS * EDG) / 256, 256, 0, stream>>>(inner_src, inner_dst, fwd_src, fwd_dst,
                                                           bwd_src, bwd_dst, rowstart, rank, elist);

    unsigned short* w13h = w1h + (size_t)3 * H * KP1;
    unsigned short* w13l = w1l + (size_t)3 * H * KP1;
    const float* b13 = b1 + 3 * H;

    auto mlp23_plain = [&](int set, int gbase_out) {
        k_mlp23<0><<<P / 64, 512, 0, stream>>>(
            H1h, H1l,
            w2h + (size_t)set * H * H, w2l + (size_t)set * H * H, b2 + set * H,
            w3h + (size_t)set * D * H, w3l + (size_t)set * D * H, b3 + set * D,
            X + (size_t)gbase_out * D,
            nullptr, nullptr, nullptr, nullptr, nullptr, 0, nullptr);
    };
    auto mlp23_fused = [&](int set, int gbase_node) {
        k_mlp23<1><<<P / 64, 512, 0, stream>>>(
            H1h, H1l,
            w2h + (size_t)set * H * H, w2l + (size_t)set * H * H, b2 + set * H,
            w3h + (size_t)set * D * H, w3l + (size_t)set * D * H, b3 + set * D,
            nullptr,
            w13h, w13l, b13, H1h, H1l, gbase_node, stat);
    };
    auto gemm1 = [&](int set) {
        k_gemm_big<false><<<dim3(H / 128, P / 128), 512, 0, stream>>>(
            Th, Tl, KP1, nullptr, nullptr, 0,
            w1h + (size_t)set * H * KP1, w1l + (size_t)set * H * KP1, KP1,
            b1 + set * H, H1h, H1l, H);
    };
    auto gather = [&](int t, int dst_gbase, int src_gbase, int ei) {
        k_gather_T<<<P / 4, 256, 0, stream>>>(
            X, stat, elist + (size_t)t * EDG, rowstart + (size_t)t * RSP,
            Th, Tl, dst_gbase, src_gbase, eps, ei);
    };

    // forward pass
    for (int il = 0; il < NLAYERS; ++il) {
        int s0 = il * P;
        gather(il, s0, s0, 0);
        gemm1(0);
        mlp23_plain(0, s0);
        if (il == NLAYERS - 1) continue;
        gather(5 + il, s0 + P, s0, 1);
        gemm1(1);
        mlp23_fused(1, s0 + P);
        mlp23_plain(3, s0 + P);
    }
    // backward pass
    for (int il = NLAYERS - 1; il >= 1; --il) {
        int s0 = (il - 1) * P;
        gather(9 + (il - 1), s0, s0 + P, 2);
        gemm1(2);
        mlp23_plain(2, s0);
        gather(il - 1, s0, s0, 0);
        gemm1(0);
        mlp23_fused(0, s0);
        mlp23_plain(3, s0);
    }

    k_pool2<<<NND / PROWS, 256, 0, stream>>>(X, bidx, PL);
    k_final<<<1, 64, 0, stream>>>(PL, lin_w, lin_b, (float*)d_out);
}

// Round 23
// 1092.695 us; speedup vs baseline: 1.4818x; 1.1094x over previous
//
#include <hip/hip_runtime.h>

#define P 16384
#define NLAYERS 5
#define NND 98304          // P*(NLAYERS+1)
#define D 64
#define S 16
#define F 80               // D+S
#define KP1 96             // K of layer-1 GEMM padded to 32
#define H 256
#define EDG 262144         // 1<<18
#define NG 64
#define NSETS 13           // 5 inner + 4 fwd + 4 bwd
#define RSP 16385          // rowstart pitch (P+1)
#define LDP 40             // LDS K-stride for 32-chunks (80B rows, <=2-way aliasing)
#define LH2 264            // H2 LDS row stride (256+8)
#define LXS 100            // X-tile LDS row stride (96+4)

typedef __attribute__((ext_vector_type(8))) _Float16 f16x8;
typedef __attribute__((ext_vector_type(4))) _Float16 f16x4;
typedef __attribute__((ext_vector_type(4))) float f32x4;

// ---------------------------------------------------------------- utilities
__device__ __forceinline__ void fatomic_add(float* p, float v) {
    unsafeAtomicAdd(p, v);
}

// ---------------------------------------------------------------- init X + zero deg + zero PL
__global__ void k_init_x(const float* __restrict__ x0, float* __restrict__ X,
                         int* __restrict__ deg, float* __restrict__ PL) {
    int idx = blockIdx.x * blockDim.x + threadIdx.x;
    if (idx < NND * D) {
        int row = idx >> 6, f = idx & 63;
        X[idx] = (f == 0) ? x0[row] : 0.0f;
        return;
    }
    int r = idx - NND * D;
    if (r < NSETS * P) { deg[r] = 0; return; }
    r -= NSETS * P;
    if (r < NG * D) PL[r] = 0.0f;
}

// ---------------------------------------------------------------- weight transpose + split-fp16 (all 3 layers)
__global__ void k_wsplit_all(const float* __restrict__ W1, const float* __restrict__ W2,
                             const float* __restrict__ W3,
                             _Float16* __restrict__ w1h, _Float16* __restrict__ w1l,
                             _Float16* __restrict__ w2h, _Float16* __restrict__ w2l,
                             _Float16* __restrict__ w3h, _Float16* __restrict__ w3l) {
    const int n1 = 4 * H * KP1, n2 = 4 * H * H, n3 = 4 * D * H;
    int idx = blockIdx.x * blockDim.x + threadIdx.x;
    const float* W; _Float16 *h, *l; int K, N, Kp, i;
    if (idx < n1)              { W = W1; h = w1h; l = w1l; K = F; N = H; Kp = KP1; i = idx; }
    else if (idx < n1 + n2)    { W = W2; h = w2h; l = w2l; K = H; N = H; Kp = H;   i = idx - n1; }
    else if (idx < n1 + n2 + n3){ W = W3; h = w3h; l = w3l; K = H; N = D; Kp = H;  i = idx - n1 - n2; }
    else return;
    int set = i / (N * Kp), rem = i - set * (N * Kp);
    int n = rem / Kp, kp = rem - n * Kp;
    float v = (kp < K) ? W[(size_t)set * K * N + (size_t)kp * N + n] : 0.0f;
    _Float16 hh = (_Float16)v;
    h[i] = hh;
    l[i] = (_Float16)(v - (float)hh);
}

// ---------------------------------------------------------------- CSR build (batched, 13 sets) — R15-proven
__device__ __forceinline__ const int* set_ptr(int t, const int* inner, const int* fwd,
                                              const int* bwd) {
    if (t < 5) return inner + (size_t)t * EDG;
    if (t < 9) return fwd + (size_t)(t - 5) * EDG;
    return bwd + (size_t)(t - 9) * EDG;
}

__global__ void k_csr_hist(const int* __restrict__ inner_dst, const int* __restrict__ fwd_dst,
                           const int* __restrict__ bwd_dst, int* __restrict__ deg,
                           int* __restrict__ rank) {
    int idx = blockIdx.x * blockDim.x + threadIdx.x;
    if (idx >= NSETS * EDG) return;
    int t = idx >> 18, e = idx & (EDG - 1);
    const int* dstp = set_ptr(t, inner_dst, fwd_dst, bwd_dst);
    rank[idx] = atomicAdd(&deg[t * P + dstp[e]], 1);
}

__global__ __launch_bounds__(1024) void k_csr_scan(const int* __restrict__ deg,
                                                   int* __restrict__ rowstart) {
    __shared__ int part[1024];
    int t = blockIdx.x;
    const int* d = deg + t * P;
    int* rs = rowstart + (size_t)t * RSP;
    int tid = threadIdx.x;
    int base = tid * 16;
    int loc[16], sum = 0;
#pragma unroll
    for (int i = 0; i < 16; ++i) { loc[i] = sum; sum += d[base + i]; }
    part[tid] = sum;
    __syncthreads();
    for (int off = 1; off < 1024; off <<= 1) {
        int v = (tid >= off) ? part[tid - off] : 0;
        __syncthreads();
        part[tid] += v;
        __syncthreads();
    }
    int pre = tid ? part[tid - 1] : 0;
#pragma unroll
    for (int i = 0; i < 16; ++i) rs[base + i] = pre + loc[i];
    if (tid == 1023) rs[P] = pre + sum;
}

__global__ void k_csr_scatter(const int* __restrict__ inner_src, const int* __restrict__ inner_dst,
                              const int* __restrict__ fwd_src, const int* __restrict__ fwd_dst,
                              const int* __restrict__ bwd_src, const int* __restrict__ bwd_dst,
                              const int* __restrict__ rowstart, const int* __restrict__ rank,
                              int* __restrict__ elist) {
    int idx = blockIdx.x * blockDim.x + threadIdx.x;
    if (idx >= NSETS * EDG) return;
    int t = idx >> 18, e = idx & (EDG - 1);
    const int* srcp = set_ptr(t, inner_src, fwd_src, bwd_src);
    const int* dstp = set_ptr(t, inner_dst, fwd_dst, bwd_dst);
    int dv = dstp[e];
    elist[(size_t)t * EDG + rowstart[(size_t)t * RSP + dv] + rank[idx]] = srcp[e];
}

// ---------------------------------------------------------------- gather conv input (wave per node, 4-row ILP) -> fp16 T
__global__ __launch_bounds__(256) void k_gather_T(const float* __restrict__ X,
                                                  const float* __restrict__ st,
                                                  const int* __restrict__ elist,
                                                  const int* __restrict__ rowstart,
                                                  _Float16* __restrict__ Th,
                                                  int dst_gbase, int src_gbase,
                                                  const float* __restrict__ eps, int ei) {
    int wv = threadIdx.x >> 6, l = threadIdx.x & 63;
    int v = blockIdx.x * 4 + wv;
    int beg = rowstart[v], end = rowstart[v + 1];
    float scale = 1.0f + eps[ei];
    int rg = l >> 4, c = l & 15;
    float ax0 = 0.f, ax1 = 0.f, ax2 = 0.f, ax3 = 0.f, as = 0.f;
    int i = beg;
    for (; i + 4 <= end; i += 4) {
        int s = src_gbase + elist[i + rg];
        float4 xv = *(const float4*)&X[(size_t)s * D + 4 * c];
        ax0 += xv.x; ax1 += xv.y; ax2 += xv.z; ax3 += xv.w;
        as += st[(size_t)s * S + c];
    }
    if (i < end) {
        int rem = end - i;
        if (rg < rem) {
            int s = src_gbase + elist[i + rg];
            float4 xv = *(const float4*)&X[(size_t)s * D + 4 * c];
            ax0 += xv.x; ax1 += xv.y; ax2 += xv.z; ax3 += xv.w;
            as += st[(size_t)s * S + c];
        }
    }
#pragma unroll
    for (int off = 16; off < 64; off <<= 1) {
        ax0 += __shfl_xor(ax0, off, 64);
        ax1 += __shfl_xor(ax1, off, 64);
        ax2 += __shfl_xor(ax2, off, 64);
        ax3 += __shfl_xor(ax3, off, 64);
        as  += __shfl_xor(as,  off, 64);
    }
    if (l < 16) {
        int g = dst_gbase + v;
        float4 sx = *(const float4*)&X[(size_t)g * D + 4 * l];
        f16x4 hv;
        hv[0] = (_Float16)(ax0 + scale * sx.x);
        hv[1] = (_Float16)(ax1 + scale * sx.y);
        hv[2] = (_Float16)(ax2 + scale * sx.z);
        hv[3] = (_Float16)(ax3 + scale * sx.w);
        *(f16x4*)&Th[(size_t)v * KP1 + 4 * l] = hv;
        Th[(size_t)v * KP1 + D + l] = (_Float16)(as + scale * st[(size_t)g * S + l]);
        Th[(size_t)v * KP1 + F + l] = (_Float16)0.0f;   // pad cols 80..95
    }
}

// ---------------------------------------------------------------- GEMM1 (128x128, 8 waves, LDS): H1 = relu(T @ W1^T + b1)
// A = fp16 single plane; B = split fp16; 2 MFMAs per combo. Out: H1 single fp16 plane.
__global__ __launch_bounds__(512) void k_gemm1(
    const _Float16* __restrict__ Tp, int lda,
    const _Float16* __restrict__ Wh, const _Float16* __restrict__ Wl, int Kp,
    const float* __restrict__ bias,
    _Float16* __restrict__ Ch, int ldc)
{
    __shared__ _Float16 Ah[128][LDP];                 // 10.2 KB
    __shared__ _Float16 Bh[128][LDP], Bl[128][LDP];   // 20.5 KB

    int tid = threadIdx.x;
    int lane = tid & 63, wid = tid >> 6;       // 8 waves
    int wm = wid >> 2, wn = wid & 3;           // 2 x 4, wave tile 64x32
    int m0 = blockIdx.y * 128, n0 = blockIdx.x * 128;

    f32x4 acc[4][2] = {};

    int ar = tid >> 2;                         // A: 1 chunk/thread
    int ac = (tid & 3) * 8;
    int la = lane & 15, lg = lane >> 4;

    for (int k0 = 0; k0 < Kp; k0 += 32) {
        *(f16x8*)&Ah[ar][ac] = *(const f16x8*)&Tp[(size_t)(m0 + ar) * lda + k0 + ac];
#pragma unroll
        for (int j = 0; j < 2; ++j) {          // B: 1024 chunks / 512 threads
            int id = j * 512 + tid;
            int bpl = id >> 9, brem = id & 511;
            int br = brem >> 2, bq = (brem & 3) * 8;
            const _Float16* src = bpl ? Wl : Wh;
            _Float16 (*dsth)[LDP] = bpl ? Bl : Bh;
            *(f16x8*)&dsth[br][bq] = *(const f16x8*)&src[(size_t)(n0 + br) * Kp + k0 + bq];
        }
        __syncthreads();

        int kf = lg * 8;
        f16x8 ah[4], bh[2], bl[2];
#pragma unroll
        for (int m = 0; m < 4; ++m) ah[m] = *(const f16x8*)&Ah[wm * 64 + m * 16 + la][kf];
#pragma unroll
        for (int n = 0; n < 2; ++n) {
            int r = wn * 32 + n * 16 + la;
            bh[n] = *(const f16x8*)&Bh[r][kf];
            bl[n] = *(const f16x8*)&Bl[r][kf];
        }
#pragma unroll
        for (int m = 0; m < 4; ++m)
#pragma unroll
            for (int n = 0; n < 2; ++n) {
                acc[m][n] = __builtin_amdgcn_mfma_f32_16x16x32_f16(ah[m], bh[n], acc[m][n], 0, 0, 0);
                acc[m][n] = __builtin_amdgcn_mfma_f32_16x16x32_f16(ah[m], bl[n], acc[m][n], 0, 0, 0);
            }
        __syncthreads();
    }

#pragma unroll
    for (int n = 0; n < 2; ++n) {
        int col = n0 + wn * 32 + n * 16 + la;
        float bv = bias[col];
#pragma unroll
        for (int m = 0; m < 4; ++m) {
            int row = m0 + wm * 64 + m * 16 + lg * 4;
#pragma unroll
            for (int r = 0; r < 4; ++r) {
                Ch[(size_t)(row + r) * ldc + col] = (_Float16)fmaxf(acc[m][n][r] + bv, 0.0f);
            }
        }
    }
}

// ---------------------------------------------------------------- fused GEMM2+GEMM3 (+optional node GEMM1), 64-row tile
// A-side fp16 single plane, B split fp16. MODE 0: X->global (80KB LDS, 2 blocks/CU).
// MODE 1: X tile in LDS; phase4 = node_dnn GEMM1 -> H1.
template<int MODE>
__global__ __launch_bounds__(512, 4) void k_mlp23(
    const _Float16* __restrict__ H1p,
    const _Float16* __restrict__ W2h, const _Float16* __restrict__ W2l,
    const float* __restrict__ b2,
    const _Float16* __restrict__ W3h, const _Float16* __restrict__ W3l,
    const float* __restrict__ b3,
    float* __restrict__ Xout,
    const _Float16* __restrict__ W1h3, const _Float16* __restrict__ W1l3,
    const float* __restrict__ b13,
    _Float16* __restrict__ H1o,
    int st_gbase, const float* __restrict__ stsrc)
{
    __shared__ _Float16 A1h[64][LDP];                  // 5.1 KB
    __shared__ _Float16 B1h[256][LDP], B1l[256][LDP];  // 41 KB (W2 / W3 / W1_3)
    __shared__ _Float16 H2hs[64][LH2];                 // 33.8 KB
    __shared__ _Float16 Xsh[(MODE == 1) ? 64 : 1][LXS];// 12.8 KB (MODE 1)

    int tid = threadIdx.x;
    int lane = tid & 63, wid = tid >> 6;
    int la = lane & 15, lg = lane >> 4;
    int r0 = blockIdx.x * 64;

    // ================= phase 1: H2 = relu(H1 @ W2^T + b2), 64x256
    f32x4 acc[4][2] = {};
    for (int k0 = 0; k0 < H; k0 += 32) {
        if (tid < 256) {                       // A: 64 rows x 4 chunks
            int ar = tid >> 2, aq = (tid & 3) * 8;
            *(f16x8*)&A1h[ar][aq] = *(const f16x8*)&H1p[(size_t)(r0 + ar) * H + k0 + aq];
        }
#pragma unroll
        for (int j = 0; j < 4; ++j) {          // B: W2 256 rows x 4 chunks x 2 planes
            int id = j * 512 + tid;
            int bpl = id >> 10, brem = id & 1023;
            int br = brem >> 2, bq = (brem & 3) * 8;
            const _Float16* src = bpl ? W2l : W2h;
            _Float16 (*dsth)[LDP] = bpl ? B1l : B1h;
            *(f16x8*)&dsth[br][bq] = *(const f16x8*)&src[(size_t)br * H + k0 + bq];
        }
        __syncthreads();

        int kf = lg * 8;
        f16x8 ah[4], bh[2], bl[2];
#pragma unroll
        for (int m = 0; m < 4; ++m) ah[m] = *(const f16x8*)&A1h[m * 16 + la][kf];
#pragma unroll
        for (int n = 0; n < 2; ++n) {
            int r = wid * 32 + n * 16 + la;
            bh[n] = *(const f16x8*)&B1h[r][kf];
            bl[n] = *(const f16x8*)&B1l[r][kf];
        }
#pragma unroll
        for (int m = 0; m < 4; ++m)
#pragma unroll
            for (int n = 0; n < 2; ++n) {
                acc[m][n] = __builtin_amdgcn_mfma_f32_16x16x32_f16(ah[m], bh[n], acc[m][n], 0, 0, 0);
                acc[m][n] = __builtin_amdgcn_mfma_f32_16x16x32_f16(ah[m], bl[n], acc[m][n], 0, 0, 0);
            }
        __syncthreads();
    }
#pragma unroll
    for (int n = 0; n < 2; ++n) {
        int col = wid * 32 + n * 16 + la;
        float bv = b2[col];
#pragma unroll
        for (int m = 0; m < 4; ++m) {
            int row = m * 16 + lg * 4;
#pragma unroll
            for (int r = 0; r < 4; ++r) {
                H2hs[row + r][col] = (_Float16)fmaxf(acc[m][n][r] + bv, 0.0f);
            }
        }
    }
    __syncthreads();

    // ================= phase 2: Xtile = relu(H2 @ W3^T + b3), K=256
    int wm = wid >> 2, wn = wid & 3;
    f32x4 acc2[2] = {};
    {
        int pl = tid >> 8, rem = tid & 255;
        int br = rem >> 2, bq = (rem & 3) * 8;   // W3: 64 rows x 4 chunks x 2 planes
        for (int k0 = 0; k0 < H; k0 += 32) {
            {
                const _Float16* src = pl ? W3l : W3h;
                _Float16 (*dsth)[LDP] = pl ? B1l : B1h;
                *(f16x8*)&dsth[br][bq] = *(const f16x8*)&src[(size_t)br * H + k0 + bq];
            }
            __syncthreads();

            int kf = lg * 8;
            f16x8 ah[2], bh, bl;
#pragma unroll
            for (int m = 0; m < 2; ++m) ah[m] = *(const f16x8*)&H2hs[wm * 32 + m * 16 + la][k0 + kf];
            {
                int r = wn * 16 + la;
                bh = *(const f16x8*)&B1h[r][kf];
                bl = *(const f16x8*)&B1l[r][kf];
            }
#pragma unroll
            for (int m = 0; m < 2; ++m) {
                acc2[m] = __builtin_amdgcn_mfma_f32_16x16x32_f16(ah[m], bh, acc2[m], 0, 0, 0);
                acc2[m] = __builtin_amdgcn_mfma_f32_16x16x32_f16(ah[m], bl, acc2[m], 0, 0, 0);
            }
            __syncthreads();
        }
    }
    {
        int col = wn * 16 + la;
        float bv = b3[col];
#pragma unroll
        for (int m = 0; m < 2; ++m) {
            int rloc = wm * 32 + m * 16 + lg * 4;
#pragma unroll
            for (int r = 0; r < 4; ++r) {
                float v = fmaxf(acc2[m][r] + bv, 0.0f);
                if (MODE == 0) {
                    Xout[(size_t)(r0 + rloc + r) * D + col] = v;
                } else {
                    Xsh[rloc + r][col] = (_Float16)v;
                }
            }
        }
    }

    if (MODE == 1) {
        {   // static cols 64..79 + zero pad 80..95 (64 rows x 16 static, 512 threads -> 2 cols/thread)
            int row = tid >> 3, c2 = (tid & 7) * 2;
            int g = st_gbase + r0 + row;
            float2 sv = *(const float2*)&stsrc[(size_t)g * S + c2];
            Xsh[row][D + c2] = (_Float16)sv.x;
            Xsh[row][D + c2 + 1] = (_Float16)sv.y;
            Xsh[row][F + c2] = (_Float16)0.0f;
            Xsh[row][F + c2 + 1] = (_Float16)0.0f;
        }
        __syncthreads();

        // phase 4: H1' = relu([X|st|0] @ W1_3^T + b1_3), 64x256, K=96
        f32x4 acc4[4][2] = {};
        for (int k0 = 0; k0 < KP1; k0 += 32) {
#pragma unroll
            for (int j = 0; j < 4; ++j) {
                int id = j * 512 + tid;
                int bpl = id >> 10, brem = id & 1023;
                int br = brem >> 2, bq = (brem & 3) * 8;
                const _Float16* src = bpl ? W1l3 : W1h3;
                _Float16 (*dsth)[LDP] = bpl ? B1l : B1h;
                *(f16x8*)&dsth[br][bq] = *(const f16x8*)&src[(size_t)br * KP1 + k0 + bq];
            }
            __syncthreads();

            int kf = lg * 8;
            f16x8 ah[4], bh[2], bl[2];
#pragma unroll
            for (int m = 0; m < 4; ++m) ah[m] = *(const f16x8*)&Xsh[m * 16 + la][k0 + kf];
#pragma unroll
            for (int n = 0; n < 2; ++n) {
                int r = wid * 32 + n * 16 + la;
                bh[n] = *(const f16x8*)&B1h[r][kf];
                bl[n] = *(const f16x8*)&B1l[r][kf];
            }
#pragma unroll
            for (int m = 0; m < 4; ++m)
#pragma unroll
                for (int n = 0; n < 2; ++n) {
                    acc4[m][n] = __builtin_amdgcn_mfma_f32_16x16x32_f16(ah[m], bh[n], acc4[m][n], 0, 0, 0);
                    acc4[m][n] = __builtin_amdgcn_mfma_f32_16x16x32_f16(ah[m], bl[n], acc4[m][n], 0, 0, 0);
                }
            __syncthreads();
        }
#pragma unroll
        for (int n = 0; n < 2; ++n) {
            int col = wid * 32 + n * 16 + la;
            float bv = b13[col];
#pragma unroll
            for (int m = 0; m < 4; ++m) {
                int row = r0 + m * 16 + lg * 4;
#pragma unroll
                for (int r = 0; r < 4; ++r) {
                    H1o[(size_t)(row + r) * H + col] = (_Float16)fmaxf(acc4[m][n][r] + bv, 0.0f);
                }
            }
        }
    }
}

// ---------------------------------------------------------------- two-stage pooling
#define PROWS 1024
__global__ __launch_bounds__(256) void k_pool2(const float* __restrict__ X,
                                               const int* __restrict__ bidx,
                                               float* __restrict__ PL) {
    __shared__ float lds[NG * D];
    int tid = threadIdx.x;
    for (int i = tid; i < NG * D; i += 256) lds[i] = 0.0f;
    __syncthreads();
    int base = blockIdx.x * PROWS;
    int f = tid & 63, rg = tid >> 6;
    for (int r = base + rg; r < base + PROWS; r += 4) {
        int g = bidx[r];
        atomicAdd(&lds[g * D + f], X[(size_t)r * D + f]);
    }
    __syncthreads();
    for (int i = tid; i < NG * D; i += 256) {
        float v = lds[i];
        if (v != 0.0f) fatomic_add(&PL[i], v);
    }
}

// ---------------------------------------------------------------- final linear head
__global__ void k_final(const float* __restrict__ pooled, const float* __restrict__ lin_w,
                        const float* __restrict__ lin_b, float* __restrict__ out) {
    int g = threadIdx.x;
    if (g >= NG) return;
    float acc = lin_b[0];
#pragma unroll
    for (int d2 = 0; d2 < D; ++d2) acc += pooled[g * D + d2] * lin_w[d2];
    out[g] = fmaxf(acc, 0.0f);
}

// ---------------------------------------------------------------- launch
extern "C" void kernel_launch(void* const* d_in, const int* in_sizes, int n_in,
                              void* d_out, int out_size, void* d_ws, size_t ws_size,
                              hipStream_t stream) {
    const float* x0    = (const float*)d_in[0];
    const float* stat  = (const float*)d_in[1];
    const float* W1    = (const float*)d_in[2];
    const float* b1    = (const float*)d_in[3];
    const float* W2    = (const float*)d_in[4];
    const float* b2    = (const float*)d_in[5];
    const float* W3    = (const float*)d_in[6];
    const float* b3    = (const float*)d_in[7];
    const float* eps   = (const float*)d_in[8];
    const float* lin_w = (const float*)d_in[9];
    const float* lin_b = (const float*)d_in[10];
    const int* inner_src = (const int*)d_in[11];
    const int* inner_dst = (const int*)d_in[12];
    const int* fwd_src   = (const int*)d_in[13];
    const int* fwd_dst   = (const int*)d_in[14];
    const int* bwd_src   = (const int*)d_in[15];
    const int* bwd_dst   = (const int*)d_in[16];
    const int* bidx      = (const int*)d_in[17];

    float* X  = (float*)d_ws;                                 // NND*64 f32
    float* PL = X + (size_t)NND * D;                          // NG*64 f32
    _Float16* Th  = (_Float16*)(PL + NG * D);                 // [P][96] single plane
    _Float16* H1p = Th + (size_t)P * KP1;                     // [P][256] single plane
    _Float16* w1h = H1p + (size_t)P * H;                      // [4][256][96] split
    _Float16* w1l = w1h + (size_t)4 * H * KP1;
    _Float16* w2h = w1l + (size_t)4 * H * KP1;                // [4][256][256] split
    _Float16* w2l = w2h + (size_t)4 * H * H;
    _Float16* w3h = w2l + (size_t)4 * H * H;                  // [4][64][256] split
    _Float16* w3l = w3h + (size_t)4 * D * H;
    int* deg      = (int*)(w3l + (size_t)4 * D * H);          // NSETS*P
    int* rowstart = deg + (size_t)NSETS * P;                  // NSETS*RSP
    int* rank     = rowstart + (size_t)NSETS * RSP;           // NSETS*EDG
    int* elist    = rank + (size_t)NSETS * EDG;               // NSETS*EDG

    // ---- init X + zero deg/PL
    {
        int tot = NND * D + NSETS * P + NG * D;
        k_init_x<<<(tot + 255) / 256, 256, 0, stream>>>(x0, X, deg, PL);
    }
    // ---- weight prep
    {
        int tot = 4 * H * KP1 + 4 * H * H + 4 * D * H;
        k_wsplit_all<<<(tot + 255) / 256, 256, 0, stream>>>(W1, W2, W3, w1h, w1l, w2h, w2l, w3h, w3l);
    }
    // ---- CSR build (R15-proven 3-kernel pipeline)
    k_csr_hist<<<(NSETS * EDG) / 256, 256, 0, stream>>>(inner_dst, fwd_dst, bwd_dst, deg, rank);
    k_csr_scan<<<NSETS, 1024, 0, stream>>>(deg, rowstart);
    k_csr_scatter<<<(NSETS * EDG) / 256, 256, 0, stream>>>(inner_src, inner_dst, fwd_src, fwd_dst,
                                                           bwd_src, bwd_dst, rowstart, rank, elist);

    _Float16* w13h = w1h + (size_t)3 * H * KP1;
    _Float16* w13l = w1l + (size_t)3 * H * KP1;
    const float* b13 = b1 + 3 * H;

    auto mlp23_plain = [&](int set, int gbase_out) {
        k_mlp23<0><<<P / 64, 512, 0, stream>>>(
            H1p,
            w2h + (size_t)set * H * H, w2l + (size_t)set * H * H, b2 + set * H,
            w3h + (size_t)set * D * H, w3l + (size_t)set * D * H, b3 + set * D,
            X + (size_t)gbase_out * D,
            nullptr, nullptr, nullptr, nullptr, 0, nullptr);
    };
    auto mlp23_fused = [&](int set, int gbase_node) {
        k_mlp23<1><<<P / 64, 512, 0, stream>>>(
            H1p,
            w2h + (size_t)set * H * H, w2l + (size_t)set * H * H, b2 + set * H,
            w3h + (size_t)set * D * H, w3l + (size_t)set * D * H, b3 + set * D,
            nullptr,
            w13h, w13l, b13, H1p, gbase_node, stat);
    };
    auto gemm1 = [&](int set) {
        k_gemm1<<<dim3(H / 128, P / 128), 512, 0, stream>>>(
            Th, KP1,
            w1h + (size_t)set * H * KP1, w1l + (size_t)set * H * KP1, KP1,
            b1 + set * H, H1p, H);
    };
    auto gather = [&](int t, int dst_gbase, int src_gbase, int ei) {
        k_gather_T<<<P / 4, 256, 0, stream>>>(
            X, stat, elist + (size_t)t * EDG, rowstart + (size_t)t * RSP,
            Th, dst_gbase, src_gbase, eps, ei);
    };

    // forward pass
    for (int il = 0; il < NLAYERS; ++il) {
        int s0 = il * P;
        gather(il, s0, s0, 0);
        gemm1(0);
        mlp23_plain(0, s0);
        if (il == NLAYERS - 1) continue;
        gather(5 + il, s0 + P, s0, 1);
        gemm1(1);
        mlp23_fused(1, s0 + P);
        mlp23_plain(3, s0 + P);
    }
    // backward pass
    for (int il = NLAYERS - 1; il >= 1; --il) {
        int s0 = (il - 1) * P;
        gather(9 + (il - 1), s0, s0 + P, 2);
        gemm1(2);
        mlp23_plain(2, s0);
        gather(il - 1, s0, s0, 0);
        gemm1(0);
        mlp23_fused(0, s0);
        mlp23_plain(3, s0);
    }

    k_pool2<<<NND / PROWS, 256, 0, stream>>>(X, bidx, PL);
    k_final<<<1, 64, 0, stream>>>(PL, lin_w, lin_b, (float*)d_out);
}

// Round 24
// 986.449 us; speedup vs baseline: 1.6414x; 1.1077x over previous
//
#include <hip/hip_runtime.h>

#define P 16384
#define NLAYERS 5
#define NND 98304          // P*(NLAYERS+1)
#define D 64
#define S 16
#define F 80               // D+S
#define KP1 96             // K of layer-1 GEMM padded to 32
#define H 256
#define EDG 262144         // 1<<18
#define NG 64
#define NSETS 13           // 5 inner + 4 fwd + 4 bwd
#define RSP 16385          // rowstart pitch (P+1)
#define LDP 40             // LDS K-stride for 32-chunks (80B rows, <=2-way aliasing)
#define LH2 264            // H2 LDS row stride (256+8)
#define LXS 100            // X-tile LDS row stride (96+4)

typedef __attribute__((ext_vector_type(8))) _Float16 f16x8;
typedef __attribute__((ext_vector_type(4))) _Float16 f16x4;
typedef __attribute__((ext_vector_type(4))) float f32x4;

// ---------------------------------------------------------------- utilities
__device__ __forceinline__ void fatomic_add(float* p, float v) {
    unsafeAtomicAdd(p, v);
}

// ---------------------------------------------------------------- init X + zero deg + zero PL
__global__ void k_init_x(const float* __restrict__ x0, float* __restrict__ X,
                         int* __restrict__ deg, float* __restrict__ PL) {
    int idx = blockIdx.x * blockDim.x + threadIdx.x;
    if (idx < NND * D) {
        int row = idx >> 6, f = idx & 63;
        X[idx] = (f == 0) ? x0[row] : 0.0f;
        return;
    }
    int r = idx - NND * D;
    if (r < NSETS * P) { deg[r] = 0; return; }
    r -= NSETS * P;
    if (r < NG * D) PL[r] = 0.0f;
}

// ---------------------------------------------------------------- weight transpose -> single fp16 (all 3 layers)
__global__ void k_wconv_all(const float* __restrict__ W1, const float* __restrict__ W2,
                            const float* __restrict__ W3,
                            _Float16* __restrict__ w1, _Float16* __restrict__ w2,
                            _Float16* __restrict__ w3) {
    const int n1 = 4 * H * KP1, n2 = 4 * H * H, n3 = 4 * D * H;
    int idx = blockIdx.x * blockDim.x + threadIdx.x;
    const float* W; _Float16* h; int K, N, Kp, i;
    if (idx < n1)              { W = W1; h = w1; K = F; N = H; Kp = KP1; i = idx; }
    else if (idx < n1 + n2)    { W = W2; h = w2; K = H; N = H; Kp = H;   i = idx - n1; }
    else if (idx < n1 + n2 + n3){ W = W3; h = w3; K = H; N = D; Kp = H;  i = idx - n1 - n2; }
    else return;
    int set = i / (N * Kp), rem = i - set * (N * Kp);
    int n = rem / Kp, kp = rem - n * Kp;
    float v = (kp < K) ? W[(size_t)set * K * N + (size_t)kp * N + n] : 0.0f;
    h[i] = (_Float16)v;
}

// ---------------------------------------------------------------- CSR build (batched, 13 sets) — R15-proven
__device__ __forceinline__ const int* set_ptr(int t, const int* inner, const int* fwd,
                                              const int* bwd) {
    if (t < 5) return inner + (size_t)t * EDG;
    if (t < 9) return fwd + (size_t)(t - 5) * EDG;
    return bwd + (size_t)(t - 9) * EDG;
}

__global__ void k_csr_hist(const int* __restrict__ inner_dst, const int* __restrict__ fwd_dst,
                           const int* __restrict__ bwd_dst, int* __restrict__ deg,
                           int* __restrict__ rank) {
    int idx = blockIdx.x * blockDim.x + threadIdx.x;
    if (idx >= NSETS * EDG) return;
    int t = idx >> 18, e = idx & (EDG - 1);
    const int* dstp = set_ptr(t, inner_dst, fwd_dst, bwd_dst);
    rank[idx] = atomicAdd(&deg[t * P + dstp[e]], 1);
}

__global__ __launch_bounds__(1024) void k_csr_scan(const int* __restrict__ deg,
                                                   int* __restrict__ rowstart) {
    __shared__ int part[1024];
    int t = blockIdx.x;
    const int* d = deg + t * P;
    int* rs = rowstart + (size_t)t * RSP;
    int tid = threadIdx.x;
    int base = tid * 16;
    int loc[16], sum = 0;
#pragma unroll
    for (int i = 0; i < 16; ++i) { loc[i] = sum; sum += d[base + i]; }
    part[tid] = sum;
    __syncthreads();
    for (int off = 1; off < 1024; off <<= 1) {
        int v = (tid >= off) ? part[tid - off] : 0;
        __syncthreads();
        part[tid] += v;
        __syncthreads();
    }
    int pre = tid ? part[tid - 1] : 0;
#pragma unroll
    for (int i = 0; i < 16; ++i) rs[base + i] = pre + loc[i];
    if (tid == 1023) rs[P] = pre + sum;
}

__global__ void k_csr_scatter(const int* __restrict__ inner_src, const int* __restrict__ inner_dst,
                              const int* __restrict__ fwd_src, const int* __restrict__ fwd_dst,
                              const int* __restrict__ bwd_src, const int* __restrict__ bwd_dst,
                              const int* __restrict__ rowstart, const int* __restrict__ rank,
                              int* __restrict__ elist) {
    int idx = blockIdx.x * blockDim.x + threadIdx.x;
    if (idx >= NSETS * EDG) return;
    int t = idx >> 18, e = idx & (EDG - 1);
    const int* srcp = set_ptr(t, inner_src, fwd_src, bwd_src);
    const int* dstp = set_ptr(t, inner_dst, fwd_dst, bwd_dst);
    int dv = dstp[e];
    elist[(size_t)t * EDG + rowstart[(size_t)t * RSP + dv] + rank[idx]] = srcp[e];
}

// ---------------------------------------------------------------- gather conv input (wave per node, 4-row ILP) -> fp16 T
__global__ __launch_bounds__(256) void k_gather_T(const float* __restrict__ X,
                                                  const float* __restrict__ st,
                                                  const int* __restrict__ elist,
                                                  const int* __restrict__ rowstart,
                                                  _Float16* __restrict__ Th,
                                                  int dst_gbase, int src_gbase,
                                                  const float* __restrict__ eps, int ei) {
    int wv = threadIdx.x >> 6, l = threadIdx.x & 63;
    int v = blockIdx.x * 4 + wv;
    int beg = rowstart[v], end = rowstart[v + 1];
    float scale = 1.0f + eps[ei];
    int rg = l >> 4, c = l & 15;
    float ax0 = 0.f, ax1 = 0.f, ax2 = 0.f, ax3 = 0.f, as = 0.f;
    int i = beg;
    for (; i + 4 <= end; i += 4) {
        int s = src_gbase + elist[i + rg];
        float4 xv = *(const float4*)&X[(size_t)s * D + 4 * c];
        ax0 += xv.x; ax1 += xv.y; ax2 += xv.z; ax3 += xv.w;
        as += st[(size_t)s * S + c];
    }
    if (i < end) {
        int rem = end - i;
        if (rg < rem) {
            int s = src_gbase + elist[i + rg];
            float4 xv = *(const float4*)&X[(size_t)s * D + 4 * c];
            ax0 += xv.x; ax1 += xv.y; ax2 += xv.z; ax3 += xv.w;
            as += st[(size_t)s * S + c];
        }
    }
#pragma unroll
    for (int off = 16; off < 64; off <<= 1) {
        ax0 += __shfl_xor(ax0, off, 64);
        ax1 += __shfl_xor(ax1, off, 64);
        ax2 += __shfl_xor(ax2, off, 64);
        ax3 += __shfl_xor(ax3, off, 64);
        as  += __shfl_xor(as,  off, 64);
    }
    if (l < 16) {
        int g = dst_gbase + v;
        float4 sx = *(const float4*)&X[(size_t)g * D + 4 * l];
        f16x4 hv;
        hv[0] = (_Float16)(ax0 + scale * sx.x);
        hv[1] = (_Float16)(ax1 + scale * sx.y);
        hv[2] = (_Float16)(ax2 + scale * sx.z);
        hv[3] = (_Float16)(ax3 + scale * sx.w);
        *(f16x4*)&Th[(size_t)v * KP1 + 4 * l] = hv;
        Th[(size_t)v * KP1 + D + l] = (_Float16)(as + scale * st[(size_t)g * S + l]);
        Th[(size_t)v * KP1 + F + l] = (_Float16)0.0f;   // pad cols 80..95
    }
}

// ---------------------------------------------------------------- GEMM1 (128x128, 8 waves, LDS): H1 = relu(T @ W1^T + b1)
// fp16 single plane A and B; 1 MFMA per fragment pair.
__global__ __launch_bounds__(512) void k_gemm1(
    const _Float16* __restrict__ Tp, int lda,
    const _Float16* __restrict__ Wp, int Kp,
    const float* __restrict__ bias,
    _Float16* __restrict__ Ch, int ldc)
{
    __shared__ _Float16 Ah[128][LDP];    // 10.2 KB
    __shared__ _Float16 Bh[128][LDP];    // 10.2 KB

    int tid = threadIdx.x;
    int lane = tid & 63, wid = tid >> 6;       // 8 waves
    int wm = wid >> 2, wn = wid & 3;           // 2 x 4, wave tile 64x32
    int m0 = blockIdx.y * 128, n0 = blockIdx.x * 128;

    f32x4 acc[4][2] = {};

    int ar = tid >> 2;                         // 1 chunk/thread per tile
    int ac = (tid & 3) * 8;
    int la = lane & 15, lg = lane >> 4;

    for (int k0 = 0; k0 < Kp; k0 += 32) {
        *(f16x8*)&Ah[ar][ac] = *(const f16x8*)&Tp[(size_t)(m0 + ar) * lda + k0 + ac];
        *(f16x8*)&Bh[ar][ac] = *(const f16x8*)&Wp[(size_t)(n0 + ar) * Kp + k0 + ac];
        __syncthreads();

        int kf = lg * 8;
        f16x8 ah[4], bh[2];
#pragma unroll
        for (int m = 0; m < 4; ++m) ah[m] = *(const f16x8*)&Ah[wm * 64 + m * 16 + la][kf];
#pragma unroll
        for (int n = 0; n < 2; ++n) bh[n] = *(const f16x8*)&Bh[wn * 32 + n * 16 + la][kf];
#pragma unroll
        for (int m = 0; m < 4; ++m)
#pragma unroll
            for (int n = 0; n < 2; ++n)
                acc[m][n] = __builtin_amdgcn_mfma_f32_16x16x32_f16(ah[m], bh[n], acc[m][n], 0, 0, 0);
        __syncthreads();
    }

#pragma unroll
    for (int n = 0; n < 2; ++n) {
        int col = n0 + wn * 32 + n * 16 + la;
        float bv = bias[col];
#pragma unroll
        for (int m = 0; m < 4; ++m) {
            int row = m0 + wm * 64 + m * 16 + lg * 4;
#pragma unroll
            for (int r = 0; r < 4; ++r) {
                Ch[(size_t)(row + r) * ldc + col] = (_Float16)fmaxf(acc[m][n][r] + bv, 0.0f);
            }
        }
    }
}

// ---------------------------------------------------------------- fused GEMM2+GEMM3 (+optional node GEMM1), 64-row tile
// fp16 single plane everywhere. MODE 0: X->global (~59KB LDS). MODE 1: + phase4 node GEMM1 (~72KB).
template<int MODE>
__global__ __launch_bounds__(512, 4) void k_mlp23(
    const _Float16* __restrict__ H1p,
    const _Float16* __restrict__ W2p, const float* __restrict__ b2,
    const _Float16* __restrict__ W3p, const float* __restrict__ b3,
    float* __restrict__ Xout,
    const _Float16* __restrict__ W1p3, const float* __restrict__ b13,
    _Float16* __restrict__ H1o,
    int st_gbase, const float* __restrict__ stsrc)
{
    __shared__ _Float16 A1h[64][LDP];                  // 5.1 KB
    __shared__ _Float16 B1h[256][LDP];                 // 20.5 KB (W2 / W3 / W1_3)
    __shared__ _Float16 H2hs[64][LH2];                 // 33.8 KB
    __shared__ _Float16 Xsh[(MODE == 1) ? 64 : 1][LXS];// 12.8 KB (MODE 1)

    int tid = threadIdx.x;
    int lane = tid & 63, wid = tid >> 6;
    int la = lane & 15, lg = lane >> 4;
    int r0 = blockIdx.x * 64;

    // ================= phase 1: H2 = relu(H1 @ W2^T + b2), 64x256
    f32x4 acc[4][2] = {};
    for (int k0 = 0; k0 < H; k0 += 32) {
        if (tid < 256) {                       // A: 64 rows x 4 chunks
            int ar = tid >> 2, aq = (tid & 3) * 8;
            *(f16x8*)&A1h[ar][aq] = *(const f16x8*)&H1p[(size_t)(r0 + ar) * H + k0 + aq];
        }
#pragma unroll
        for (int j = 0; j < 2; ++j) {          // B: W2 256 rows x 4 chunks = 1024 / 512 threads
            int id = j * 512 + tid;
            int br = id >> 2, bq = (id & 3) * 8;
            *(f16x8*)&B1h[br][bq] = *(const f16x8*)&W2p[(size_t)br * H + k0 + bq];
        }
        __syncthreads();

        int kf = lg * 8;
        f16x8 ah[4], bh[2];
#pragma unroll
        for (int m = 0; m < 4; ++m) ah[m] = *(const f16x8*)&A1h[m * 16 + la][kf];
#pragma unroll
        for (int n = 0; n < 2; ++n) bh[n] = *(const f16x8*)&B1h[wid * 32 + n * 16 + la][kf];
#pragma unroll
        for (int m = 0; m < 4; ++m)
#pragma unroll
            for (int n = 0; n < 2; ++n)
                acc[m][n] = __builtin_amdgcn_mfma_f32_16x16x32_f16(ah[m], bh[n], acc[m][n], 0, 0, 0);
        __syncthreads();
    }
#pragma unroll
    for (int n = 0; n < 2; ++n) {
        int col = wid * 32 + n * 16 + la;
        float bv = b2[col];
#pragma unroll
        for (int m = 0; m < 4; ++m) {
            int row = m * 16 + lg * 4;
#pragma unroll
            for (int r = 0; r < 4; ++r) {
                H2hs[row + r][col] = (_Float16)fmaxf(acc[m][n][r] + bv, 0.0f);
            }
        }
    }
    __syncthreads();

    // ================= phase 2: Xtile = relu(H2 @ W3^T + b3), K=256
    int wm = wid >> 2, wn = wid & 3;
    f32x4 acc2[2] = {};
    {
        for (int k0 = 0; k0 < H; k0 += 32) {
            if (tid < 256) {                   // W3: 64 rows x 4 chunks
                int br = tid >> 2, bq = (tid & 3) * 8;
                *(f16x8*)&B1h[br][bq] = *(const f16x8*)&W3p[(size_t)br * H + k0 + bq];
            }
            __syncthreads();

            int kf = lg * 8;
            f16x8 ah[2], bh;
#pragma unroll
            for (int m = 0; m < 2; ++m) ah[m] = *(const f16x8*)&H2hs[wm * 32 + m * 16 + la][k0 + kf];
            bh = *(const f16x8*)&B1h[wn * 16 + la][kf];
#pragma unroll
            for (int m = 0; m < 2; ++m)
                acc2[m] = __builtin_amdgcn_mfma_f32_16x16x32_f16(ah[m], bh, acc2[m], 0, 0, 0);
            __syncthreads();
        }
    }
    {
        int col = wn * 16 + la;
        float bv = b3[col];
#pragma unroll
        for (int m = 0; m < 2; ++m) {
            int rloc = wm * 32 + m * 16 + lg * 4;
#pragma unroll
            for (int r = 0; r < 4; ++r) {
                float v = fmaxf(acc2[m][r] + bv, 0.0f);
                if (MODE == 0) {
                    Xout[(size_t)(r0 + rloc + r) * D + col] = v;
                } else {
                    Xsh[rloc + r][col] = (_Float16)v;
                }
            }
        }
    }

    if (MODE == 1) {
        {   // static cols 64..79 + zero pad 80..95
            int row = tid >> 3, c2 = (tid & 7) * 2;
            int g = st_gbase + r0 + row;
            float2 sv = *(const float2*)&stsrc[(size_t)g * S + c2];
            Xsh[row][D + c2] = (_Float16)sv.x;
            Xsh[row][D + c2 + 1] = (_Float16)sv.y;
            Xsh[row][F + c2] = (_Float16)0.0f;
            Xsh[row][F + c2 + 1] = (_Float16)0.0f;
        }
        __syncthreads();

        // phase 4: H1' = relu([X|st|0] @ W1_3^T + b1_3), 64x256, K=96
        f32x4 acc4[4][2] = {};
        for (int k0 = 0; k0 < KP1; k0 += 32) {
#pragma unroll
            for (int j = 0; j < 2; ++j) {      // W1_3: 256 rows x 4 chunks
                int id = j * 512 + tid;
                int br = id >> 2, bq = (id & 3) * 8;
                *(f16x8*)&B1h[br][bq] = *(const f16x8*)&W1p3[(size_t)br * KP1 + k0 + bq];
            }
            __syncthreads();

            int kf = lg * 8;
            f16x8 ah[4], bh[2];
#pragma unroll
            for (int m = 0; m < 4; ++m) ah[m] = *(const f16x8*)&Xsh[m * 16 + la][k0 + kf];
#pragma unroll
            for (int n = 0; n < 2; ++n) bh[n] = *(const f16x8*)&B1h[wid * 32 + n * 16 + la][kf];
#pragma unroll
            for (int m = 0; m < 4; ++m)
#pragma unroll
                for (int n = 0; n < 2; ++n)
                    acc4[m][n] = __builtin_amdgcn_mfma_f32_16x16x32_f16(ah[m], bh[n], acc4[m][n], 0, 0, 0);
            __syncthreads();
        }
#pragma unroll
        for (int n = 0; n < 2; ++n) {
            int col = wid * 32 + n * 16 + la;
            float bv = b13[col];
#pragma unroll
            for (int m = 0; m < 4; ++m) {
                int row = r0 + m * 16 + lg * 4;
#pragma unroll
                for (int r = 0; r < 4; ++r) {
                    H1o[(size_t)(row + r) * H + col] = (_Float16)fmaxf(acc4[m][n][r] + bv, 0.0f);
                }
            }
        }
    }
}

// ---------------------------------------------------------------- two-stage pooling
#define PROWS 1024
__global__ __launch_bounds__(256) void k_pool2(const float* __restrict__ X,
                                               const int* __restrict__ bidx,
                                               float* __restrict__ PL) {
    __shared__ float lds[NG * D];
    int tid = threadIdx.x;
    for (int i = tid; i < NG * D; i += 256) lds[i] = 0.0f;
    __syncthreads();
    int base = blockIdx.x * PROWS;
    int f = tid & 63, rg = tid >> 6;
    for (int r = base + rg; r < base + PROWS; r += 4) {
        int g = bidx[r];
        atomicAdd(&lds[g * D + f], X[(size_t)r * D + f]);
    }
    __syncthreads();
    for (int i = tid; i < NG * D; i += 256) {
        float v = lds[i];
        if (v != 0.0f) fatomic_add(&PL[i], v);
    }
}

// ---------------------------------------------------------------- final linear head
__global__ void k_final(const float* __restrict__ pooled, const float* __restrict__ lin_w,
                        const float* __restrict__ lin_b, float* __restrict__ out) {
    int g = threadIdx.x;
    if (g >= NG) return;
    float acc = lin_b[0];
#pragma unroll
    for (int d2 = 0; d2 < D; ++d2) acc += pooled[g * D + d2] * lin_w[d2];
    out[g] = fmaxf(acc, 0.0f);
}

// ---------------------------------------------------------------- launch
extern "C" void kernel_launch(void* const* d_in, const int* in_sizes, int n_in,
                              void* d_out, int out_size, void* d_ws, size_t ws_size,
                              hipStream_t stream) {
    const float* x0    = (const float*)d_in[0];
    const float* stat  = (const float*)d_in[1];
    const float* W1    = (const float*)d_in[2];
    const float* b1    = (const float*)d_in[3];
    const float* W2    = (const float*)d_in[4];
    const float* b2    = (const float*)d_in[5];
    const float* W3    = (const float*)d_in[6];
    const float* b3    = (const float*)d_in[7];
    const float* eps   = (const float*)d_in[8];
    const float* lin_w = (const float*)d_in[9];
    const float* lin_b = (const float*)d_in[10];
    const int* inner_src = (const int*)d_in[11];
    const int* inner_dst = (const int*)d_in[12];
    const int* fwd_src   = (const int*)d_in[13];
    const int* fwd_dst   = (const int*)d_in[14];
    const int* bwd_src   = (const int*)d_in[15];
    const int* bwd_dst   = (const int*)d_in[16];
    const int* bidx      = (const int*)d_in[17];

    float* X  = (float*)d_ws;                                 // NND*64 f32
    float* PL = X + (size_t)NND * D;                          // NG*64 f32
    _Float16* Th  = (_Float16*)(PL + NG * D);                 // [P][96]
    _Float16* H1p = Th + (size_t)P * KP1;                     // [P][256]
    _Float16* w1p = H1p + (size_t)P * H;                      // [4][256][96]
    _Float16* w2p = w1p + (size_t)4 * H * KP1;                // [4][256][256]
    _Float16* w3p = w2p + (size_t)4 * H * H;                  // [4][64][256]
    int* deg      = (int*)(w3p + (size_t)4 * D * H);          // NSETS*P
    int* rowstart = deg + (size_t)NSETS * P;                  // NSETS*RSP
    int* rank     = rowstart + (size_t)NSETS * RSP;           // NSETS*EDG
    int* elist    = rank + (size_t)NSETS * EDG;               // NSETS*EDG

    // ---- init X + zero deg/PL
    {
        int tot = NND * D + NSETS * P + NG * D;
        k_init_x<<<(tot + 255) / 256, 256, 0, stream>>>(x0, X, deg, PL);
    }
    // ---- weight prep (single fp16)
    {
        int tot = 4 * H * KP1 + 4 * H * H + 4 * D * H;
        k_wconv_all<<<(tot + 255) / 256, 256, 0, stream>>>(W1, W2, W3, w1p, w2p, w3p);
    }
    // ---- CSR build (R15-proven 3-kernel pipeline)
    k_csr_hist<<<(NSETS * EDG) / 256, 256, 0, stream>>>(inner_dst, fwd_dst, bwd_dst, deg, rank);
    k_csr_scan<<<NSETS, 1024, 0, stream>>>(deg, rowstart);
    k_csr_scatter<<<(NSETS * EDG) / 256, 256, 0, stream>>>(inner_src, inner_dst, fwd_src, fwd_dst,
                                                           bwd_src, bwd_dst, rowstart, rank, elist);

    _Float16* w13p = w1p + (size_t)3 * H * KP1;
    const float* b13 = b1 + 3 * H;

    auto mlp23_plain = [&](int set, int gbase_out) {
        k_mlp23<0><<<P / 64, 512, 0, stream>>>(
            H1p,
            w2p + (size_t)set * H * H, b2 + set * H,
            w3p + (size_t)set * D * H, b3 + set * D,
            X + (size_t)gbase_out * D,
            nullptr, nullptr, nullptr, 0, nullptr);
    };
    auto mlp23_fused = [&](int set, int gbase_node) {
        k_mlp23<1><<<P / 64, 512, 0, stream>>>(
            H1p,
            w2p + (size_t)set * H * H, b2 + set * H,
            w3p + (size_t)set * D * H, b3 + set * D,
            nullptr,
            w13p, b13, H1p, gbase_node, stat);
    };
    auto gemm1 = [&](int set) {
        k_gemm1<<<dim3(H / 128, P / 128), 512, 0, stream>>>(
            Th, KP1,
            w1p + (size_t)set * H * KP1, KP1,
            b1 + set * H, H1p, H);
    };
    auto gather = [&](int t, int dst_gbase, int src_gbase, int ei) {
        k_gather_T<<<P / 4, 256, 0, stream>>>(
            X, stat, elist + (size_t)t * EDG, rowstart + (size_t)t * RSP,
            Th, dst_gbase, src_gbase, eps, ei);
    };

    // forward pass
    for (int il = 0; il < NLAYERS; ++il) {
        int s0 = il * P;
        gather(il, s0, s0, 0);
        gemm1(0);
        mlp23_plain(0, s0);
        if (il == NLAYERS - 1) continue;
        gather(5 + il, s0 + P, s0, 1);
        gemm1(1);
        mlp23_fused(1, s0 + P);
        mlp23_plain(3, s0 + P);
    }
    // backward pass
    for (int il = NLAYERS - 1; il >= 1; --il) {
        int s0 = (il - 1) * P;
        gather(9 + (il - 1), s0, s0 + P, 2);
        gemm1(2);
        mlp23_plain(2, s0);
        gather(il - 1, s0, s0, 0);
        gemm1(0);
        mlp23_fused(0, s0);
        mlp23_plain(3, s0);
    }

    k_pool2<<<NND / PROWS, 256, 0, stream>>>(X, bidx, PL);
    k_final<<<1, 64, 0, stream>>>(PL, lin_w, lin_b, (float*)d_out);
}

// Round 25
// 923.651 us; speedup vs baseline: 1.7530x; 1.0680x over previous
//
#include <hip/hip_runtime.h>

#define P 16384
#define NLAYERS 5
#define NND 98304          // P*(NLAYERS+1)
#define D 64
#define S 16
#define F 80               // D+S
#define KP1 96             // K of layer-1 GEMM padded to 32
#define H 256
#define EDG 262144         // 1<<18
#define NG 64
#define NSETS 13           // 5 inner + 4 fwd + 4 bwd
#define RSP 16385          // rowstart pitch (P+1)
#define LDP 40             // LDS K-stride for 32-chunks (80B rows, <=2-way aliasing)
#define LH2 264            // H1s/H2s LDS row stride (256+8)
#define LXS 100            // X-tile LDS row stride (96+4)

typedef __attribute__((ext_vector_type(8))) _Float16 f16x8;
typedef __attribute__((ext_vector_type(4))) _Float16 f16x4;
typedef __attribute__((ext_vector_type(4))) float f32x4;

// ---------------------------------------------------------------- utilities
__device__ __forceinline__ void fatomic_add(float* p, float v) {
    unsafeAtomicAdd(p, v);
}

// ---------------------------------------------------------------- init X + zero deg + zero PL
__global__ void k_init_x(const float* __restrict__ x0, float* __restrict__ X,
                         int* __restrict__ deg, float* __restrict__ PL) {
    int idx = blockIdx.x * blockDim.x + threadIdx.x;
    if (idx < NND * D) {
        int row = idx >> 6, f = idx & 63;
        X[idx] = (f == 0) ? x0[row] : 0.0f;
        return;
    }
    int r = idx - NND * D;
    if (r < NSETS * P) { deg[r] = 0; return; }
    r -= NSETS * P;
    if (r < NG * D) PL[r] = 0.0f;
}

// ---------------------------------------------------------------- weight transpose -> single fp16 (all 3 layers)
__global__ void k_wconv_all(const float* __restrict__ W1, const float* __restrict__ W2,
                            const float* __restrict__ W3,
                            _Float16* __restrict__ w1, _Float16* __restrict__ w2,
                            _Float16* __restrict__ w3) {
    const int n1 = 4 * H * KP1, n2 = 4 * H * H, n3 = 4 * D * H;
    int idx = blockIdx.x * blockDim.x + threadIdx.x;
    const float* W; _Float16* h; int K, N, Kp, i;
    if (idx < n1)              { W = W1; h = w1; K = F; N = H; Kp = KP1; i = idx; }
    else if (idx < n1 + n2)    { W = W2; h = w2; K = H; N = H; Kp = H;   i = idx - n1; }
    else if (idx < n1 + n2 + n3){ W = W3; h = w3; K = H; N = D; Kp = H;  i = idx - n1 - n2; }
    else return;
    int set = i / (N * Kp), rem = i - set * (N * Kp);
    int n = rem / Kp, kp = rem - n * Kp;
    float v = (kp < K) ? W[(size_t)set * K * N + (size_t)kp * N + n] : 0.0f;
    h[i] = (_Float16)v;
}

// ---------------------------------------------------------------- CSR build (batched, 13 sets) — R15-proven
__device__ __forceinline__ const int* set_ptr(int t, const int* inner, const int* fwd,
                                              const int* bwd) {
    if (t < 5) return inner + (size_t)t * EDG;
    if (t < 9) return fwd + (size_t)(t - 5) * EDG;
    return bwd + (size_t)(t - 9) * EDG;
}

__global__ void k_csr_hist(const int* __restrict__ inner_dst, const int* __restrict__ fwd_dst,
                           const int* __restrict__ bwd_dst, int* __restrict__ deg,
                           int* __restrict__ rank) {
    int idx = blockIdx.x * blockDim.x + threadIdx.x;
    if (idx >= NSETS * EDG) return;
    int t = idx >> 18, e = idx & (EDG - 1);
    const int* dstp = set_ptr(t, inner_dst, fwd_dst, bwd_dst);
    rank[idx] = atomicAdd(&deg[t * P + dstp[e]], 1);
}

__global__ __launch_bounds__(1024) void k_csr_scan(const int* __restrict__ deg,
                                                   int* __restrict__ rowstart) {
    __shared__ int part[1024];
    int t = blockIdx.x;
    const int* d = deg + t * P;
    int* rs = rowstart + (size_t)t * RSP;
    int tid = threadIdx.x;
    int base = tid * 16;
    int loc[16], sum = 0;
#pragma unroll
    for (int i = 0; i < 16; ++i) { loc[i] = sum; sum += d[base + i]; }
    part[tid] = sum;
    __syncthreads();
    for (int off = 1; off < 1024; off <<= 1) {
        int v = (tid >= off) ? part[tid - off] : 0;
        __syncthreads();
        part[tid] += v;
        __syncthreads();
    }
    int pre = tid ? part[tid - 1] : 0;
#pragma unroll
    for (int i = 0; i < 16; ++i) rs[base + i] = pre + loc[i];
    if (tid == 1023) rs[P] = pre + sum;
}

__global__ void k_csr_scatter(const int* __restrict__ inner_src, const int* __restrict__ inner_dst,
                              const int* __restrict__ fwd_src, const int* __restrict__ fwd_dst,
                              const int* __restrict__ bwd_src, const int* __restrict__ bwd_dst,
                              const int* __restrict__ rowstart, const int* __restrict__ rank,
                              int* __restrict__ elist) {
    int idx = blockIdx.x * blockDim.x + threadIdx.x;
    if (idx >= NSETS * EDG) return;
    int t = idx >> 18, e = idx & (EDG - 1);
    const int* srcp = set_ptr(t, inner_src, fwd_src, bwd_src);
    const int* dstp = set_ptr(t, inner_dst, fwd_dst, bwd_dst);
    int dv = dstp[e];
    elist[(size_t)t * EDG + rowstart[(size_t)t * RSP + dv] + rank[idx]] = srcp[e];
}

// ---------------------------------------------------------------- gather conv input (wave per node, 4-row ILP) -> fp16 T
__global__ __launch_bounds__(256) void k_gather_T(const float* __restrict__ X,
                                                  const float* __restrict__ st,
                                                  const int* __restrict__ elist,
                                                  const int* __restrict__ rowstart,
                                                  _Float16* __restrict__ Th,
                                                  int dst_gbase, int src_gbase,
                                                  const float* __restrict__ eps, int ei) {
    int wv = threadIdx.x >> 6, l = threadIdx.x & 63;
    int v = blockIdx.x * 4 + wv;
    int beg = rowstart[v], end = rowstart[v + 1];
    float scale = 1.0f + eps[ei];
    int rg = l >> 4, c = l & 15;
    float ax0 = 0.f, ax1 = 0.f, ax2 = 0.f, ax3 = 0.f, as = 0.f;
    int i = beg;
    for (; i + 4 <= end; i += 4) {
        int s = src_gbase + elist[i + rg];
        float4 xv = *(const float4*)&X[(size_t)s * D + 4 * c];
        ax0 += xv.x; ax1 += xv.y; ax2 += xv.z; ax3 += xv.w;
        as += st[(size_t)s * S + c];
    }
    if (i < end) {
        int rem = end - i;
        if (rg < rem) {
            int s = src_gbase + elist[i + rg];
            float4 xv = *(const float4*)&X[(size_t)s * D + 4 * c];
            ax0 += xv.x; ax1 += xv.y; ax2 += xv.z; ax3 += xv.w;
            as += st[(size_t)s * S + c];
        }
    }
#pragma unroll
    for (int off = 16; off < 64; off <<= 1) {
        ax0 += __shfl_xor(ax0, off, 64);
        ax1 += __shfl_xor(ax1, off, 64);
        ax2 += __shfl_xor(ax2, off, 64);
        ax3 += __shfl_xor(ax3, off, 64);
        as  += __shfl_xor(as,  off, 64);
    }
    if (l < 16) {
        int g = dst_gbase + v;
        float4 sx = *(const float4*)&X[(size_t)g * D + 4 * l];
        f16x4 hv;
        hv[0] = (_Float16)(ax0 + scale * sx.x);
        hv[1] = (_Float16)(ax1 + scale * sx.y);
        hv[2] = (_Float16)(ax2 + scale * sx.z);
        hv[3] = (_Float16)(ax3 + scale * sx.w);
        *(f16x4*)&Th[(size_t)v * KP1 + 4 * l] = hv;
        Th[(size_t)v * KP1 + D + l] = (_Float16)(as + scale * st[(size_t)g * S + l]);
        Th[(size_t)v * KP1 + F + l] = (_Float16)0.0f;   // pad cols 80..95
    }
}

// ---------------------------------------------------------------- fused conv MLP: T -> H1(LDS) -> H2(LDS) -> X
// 64-row tile, 8 waves, 1 block/CU. MODE 0: X->global. MODE 1: X in LDS; phase4 node GEMM1 -> global H1.
template<int MODE>
__global__ __launch_bounds__(512, 2) void k_mlp123(
    const _Float16* __restrict__ Tp,
    const _Float16* __restrict__ W1p, const float* __restrict__ b1,
    const _Float16* __restrict__ W2p, const float* __restrict__ b2,
    const _Float16* __restrict__ W3p, const float* __restrict__ b3,
    float* __restrict__ Xout,
    const _Float16* __restrict__ W1p3, const float* __restrict__ b13,
    _Float16* __restrict__ H1o,
    int st_gbase, const float* __restrict__ stsrc)
{
    __shared__ _Float16 A1h[64][LDP];                  // 5.1 KB (T k-chunk staging)
    __shared__ _Float16 B1h[256][LDP];                 // 20.5 KB (W1 / W2 / W3 / W1_3)
    __shared__ _Float16 H1s[64][LH2];                  // 33.8 KB
    __shared__ _Float16 H2hs[64][LH2];                 // 33.8 KB
    __shared__ _Float16 Xsh[(MODE == 1) ? 64 : 1][LXS];// 12.8 KB (MODE 1)  -> 93 / 106 KB

    int tid = threadIdx.x;
    int lane = tid & 63, wid = tid >> 6;
    int la = lane & 15, lg = lane >> 4;
    int r0 = blockIdx.x * 64;

    // ================= phase 0: H1s = relu(T @ W1^T + b1), 64x256, K=96
    {
        f32x4 acc0[4][2] = {};
        for (int k0 = 0; k0 < KP1; k0 += 32) {
            if (tid < 256) {                   // A: T 64 rows x 4 chunks
                int ar = tid >> 2, aq = (tid & 3) * 8;
                *(f16x8*)&A1h[ar][aq] = *(const f16x8*)&Tp[(size_t)(r0 + ar) * KP1 + k0 + aq];
            }
#pragma unroll
            for (int j = 0; j < 2; ++j) {      // B: W1 256 rows x 4 chunks
                int id = j * 512 + tid;
                int br = id >> 2, bq = (id & 3) * 8;
                *(f16x8*)&B1h[br][bq] = *(const f16x8*)&W1p[(size_t)br * KP1 + k0 + bq];
            }
            __syncthreads();

            int kf = lg * 8;
            f16x8 ah[4], bh[2];
#pragma unroll
            for (int m = 0; m < 4; ++m) ah[m] = *(const f16x8*)&A1h[m * 16 + la][kf];
#pragma unroll
            for (int n = 0; n < 2; ++n) bh[n] = *(const f16x8*)&B1h[wid * 32 + n * 16 + la][kf];
#pragma unroll
            for (int m = 0; m < 4; ++m)
#pragma unroll
                for (int n = 0; n < 2; ++n)
                    acc0[m][n] = __builtin_amdgcn_mfma_f32_16x16x32_f16(ah[m], bh[n], acc0[m][n], 0, 0, 0);
            __syncthreads();
        }
#pragma unroll
        for (int n = 0; n < 2; ++n) {
            int col = wid * 32 + n * 16 + la;
            float bv = b1[col];
#pragma unroll
            for (int m = 0; m < 4; ++m) {
                int row = m * 16 + lg * 4;
#pragma unroll
                for (int r = 0; r < 4; ++r) {
                    H1s[row + r][col] = (_Float16)fmaxf(acc0[m][n][r] + bv, 0.0f);
                }
            }
        }
        __syncthreads();
    }

    // ================= phase 1: H2 = relu(H1s @ W2^T + b2), 64x256, K=256 (A read from LDS directly)
    f32x4 acc[4][2] = {};
    for (int k0 = 0; k0 < H; k0 += 32) {
#pragma unroll
        for (int j = 0; j < 2; ++j) {          // B: W2 256 rows x 4 chunks
            int id = j * 512 + tid;
            int br = id >> 2, bq = (id & 3) * 8;
            *(f16x8*)&B1h[br][bq] = *(const f16x8*)&W2p[(size_t)br * H + k0 + bq];
        }
        __syncthreads();

        int kf = lg * 8;
        f16x8 ah[4], bh[2];
#pragma unroll
        for (int m = 0; m < 4; ++m) ah[m] = *(const f16x8*)&H1s[m * 16 + la][k0 + kf];
#pragma unroll
        for (int n = 0; n < 2; ++n) bh[n] = *(const f16x8*)&B1h[wid * 32 + n * 16 + la][kf];
#pragma unroll
        for (int m = 0; m < 4; ++m)
#pragma unroll
            for (int n = 0; n < 2; ++n)
                acc[m][n] = __builtin_amdgcn_mfma_f32_16x16x32_f16(ah[m], bh[n], acc[m][n], 0, 0, 0);
        __syncthreads();
    }
#pragma unroll
    for (int n = 0; n < 2; ++n) {
        int col = wid * 32 + n * 16 + la;
        float bv = b2[col];
#pragma unroll
        for (int m = 0; m < 4; ++m) {
            int row = m * 16 + lg * 4;
#pragma unroll
            for (int r = 0; r < 4; ++r) {
                H2hs[row + r][col] = (_Float16)fmaxf(acc[m][n][r] + bv, 0.0f);
            }
        }
    }
    __syncthreads();

    // ================= phase 2: Xtile = relu(H2 @ W3^T + b3), K=256
    int wm = wid >> 2, wn = wid & 3;
    f32x4 acc2[2] = {};
    {
        for (int k0 = 0; k0 < H; k0 += 32) {
            if (tid < 256) {                   // W3: 64 rows x 4 chunks
                int br = tid >> 2, bq = (tid & 3) * 8;
                *(f16x8*)&B1h[br][bq] = *(const f16x8*)&W3p[(size_t)br * H + k0 + bq];
            }
            __syncthreads();

            int kf = lg * 8;
            f16x8 ah[2], bh;
#pragma unroll
            for (int m = 0; m < 2; ++m) ah[m] = *(const f16x8*)&H2hs[wm * 32 + m * 16 + la][k0 + kf];
            bh = *(const f16x8*)&B1h[wn * 16 + la][kf];
#pragma unroll
            for (int m = 0; m < 2; ++m)
                acc2[m] = __builtin_amdgcn_mfma_f32_16x16x32_f16(ah[m], bh, acc2[m], 0, 0, 0);
            __syncthreads();
        }
    }
    {
        int col = wn * 16 + la;
        float bv = b3[col];
#pragma unroll
        for (int m = 0; m < 2; ++m) {
            int rloc = wm * 32 + m * 16 + lg * 4;
#pragma unroll
            for (int r = 0; r < 4; ++r) {
                float v = fmaxf(acc2[m][r] + bv, 0.0f);
                if (MODE == 0) {
                    Xout[(size_t)(r0 + rloc + r) * D + col] = v;
                } else {
                    Xsh[rloc + r][col] = (_Float16)v;
                }
            }
        }
    }

    if (MODE == 1) {
        {   // static cols 64..79 + zero pad 80..95
            int row = tid >> 3, c2 = (tid & 7) * 2;
            int g = st_gbase + r0 + row;
            float2 sv = *(const float2*)&stsrc[(size_t)g * S + c2];
            Xsh[row][D + c2] = (_Float16)sv.x;
            Xsh[row][D + c2 + 1] = (_Float16)sv.y;
            Xsh[row][F + c2] = (_Float16)0.0f;
            Xsh[row][F + c2 + 1] = (_Float16)0.0f;
        }
        __syncthreads();

        // phase 4: H1' = relu([X|st|0] @ W1_3^T + b1_3), 64x256, K=96
        f32x4 acc4[4][2] = {};
        for (int k0 = 0; k0 < KP1; k0 += 32) {
#pragma unroll
            for (int j = 0; j < 2; ++j) {      // W1_3: 256 rows x 4 chunks
                int id = j * 512 + tid;
                int br = id >> 2, bq = (id & 3) * 8;
                *(f16x8*)&B1h[br][bq] = *(const f16x8*)&W1p3[(size_t)br * KP1 + k0 + bq];
            }
            __syncthreads();

            int kf = lg * 8;
            f16x8 ah[4], bh[2];
#pragma unroll
            for (int m = 0; m < 4; ++m) ah[m] = *(const f16x8*)&Xsh[m * 16 + la][k0 + kf];
#pragma unroll
            for (int n = 0; n < 2; ++n) bh[n] = *(const f16x8*)&B1h[wid * 32 + n * 16 + la][kf];
#pragma unroll
            for (int m = 0; m < 4; ++m)
#pragma unroll
                for (int n = 0; n < 2; ++n)
                    acc4[m][n] = __builtin_amdgcn_mfma_f32_16x16x32_f16(ah[m], bh[n], acc4[m][n], 0, 0, 0);
            __syncthreads();
        }
#pragma unroll
        for (int n = 0; n < 2; ++n) {
            int col = wid * 32 + n * 16 + la;
            float bv = b13[col];
#pragma unroll
            for (int m = 0; m < 4; ++m) {
                int row = r0 + m * 16 + lg * 4;
#pragma unroll
                for (int r = 0; r < 4; ++r) {
                    H1o[(size_t)(row + r) * H + col] = (_Float16)fmaxf(acc4[m][n][r] + bv, 0.0f);
                }
            }
        }
    }
}

// ---------------------------------------------------------------- node_dnn GEMM2+GEMM3 (reads global H1), 64-row tile — R24-proven
__global__ __launch_bounds__(512, 4) void k_mlp23(
    const _Float16* __restrict__ H1p,
    const _Float16* __restrict__ W2p, const float* __restrict__ b2,
    const _Float16* __restrict__ W3p, const float* __restrict__ b3,
    float* __restrict__ Xout)
{
    __shared__ _Float16 A1h[64][LDP];                  // 5.1 KB
    __shared__ _Float16 B1h[256][LDP];                 // 20.5 KB
    __shared__ _Float16 H2hs[64][LH2];                 // 33.8 KB

    int tid = threadIdx.x;
    int lane = tid & 63, wid = tid >> 6;
    int la = lane & 15, lg = lane >> 4;
    int r0 = blockIdx.x * 64;

    // phase 1: H2 = relu(H1 @ W2^T + b2)
    f32x4 acc[4][2] = {};
    for (int k0 = 0; k0 < H; k0 += 32) {
        if (tid < 256) {
            int ar = tid >> 2, aq = (tid & 3) * 8;
            *(f16x8*)&A1h[ar][aq] = *(const f16x8*)&H1p[(size_t)(r0 + ar) * H + k0 + aq];
        }
#pragma unroll
        for (int j = 0; j < 2; ++j) {
            int id = j * 512 + tid;
            int br = id >> 2, bq = (id & 3) * 8;
            *(f16x8*)&B1h[br][bq] = *(const f16x8*)&W2p[(size_t)br * H + k0 + bq];
        }
        __syncthreads();

        int kf = lg * 8;
        f16x8 ah[4], bh[2];
#pragma unroll
        for (int m = 0; m < 4; ++m) ah[m] = *(const f16x8*)&A1h[m * 16 + la][kf];
#pragma unroll
        for (int n = 0; n < 2; ++n) bh[n] = *(const f16x8*)&B1h[wid * 32 + n * 16 + la][kf];
#pragma unroll
        for (int m = 0; m < 4; ++m)
#pragma unroll
            for (int n = 0; n < 2; ++n)
                acc[m][n] = __builtin_amdgcn_mfma_f32_16x16x32_f16(ah[m], bh[n], acc[m][n], 0, 0, 0);
        __syncthreads();
    }
#pragma unroll
    for (int n = 0; n < 2; ++n) {
        int col = wid * 32 + n * 16 + la;
        float bv = b2[col];
#pragma unroll
        for (int m = 0; m < 4; ++m) {
            int row = m * 16 + lg * 4;
#pragma unroll
            for (int r = 0; r < 4; ++r) {
                H2hs[row + r][col] = (_Float16)fmaxf(acc[m][n][r] + bv, 0.0f);
            }
        }
    }
    __syncthreads();

    // phase 2: X = relu(H2 @ W3^T + b3)
    int wm = wid >> 2, wn = wid & 3;
    f32x4 acc2[2] = {};
    for (int k0 = 0; k0 < H; k0 += 32) {
        if (tid < 256) {
            int br = tid >> 2, bq = (tid & 3) * 8;
            *(f16x8*)&B1h[br][bq] = *(const f16x8*)&W3p[(size_t)br * H + k0 + bq];
        }
        __syncthreads();

        int kf = lg * 8;
        f16x8 ah[2], bh;
#pragma unroll
        for (int m = 0; m < 2; ++m) ah[m] = *(const f16x8*)&H2hs[wm * 32 + m * 16 + la][k0 + kf];
        bh = *(const f16x8*)&B1h[wn * 16 + la][kf];
#pragma unroll
        for (int m = 0; m < 2; ++m)
            acc2[m] = __builtin_amdgcn_mfma_f32_16x16x32_f16(ah[m], bh, acc2[m], 0, 0, 0);
        __syncthreads();
    }
    {
        int col = wn * 16 + la;
        float bv = b3[col];
#pragma unroll
        for (int m = 0; m < 2; ++m) {
            int rloc = wm * 32 + m * 16 + lg * 4;
#pragma unroll
            for (int r = 0; r < 4; ++r) {
                Xout[(size_t)(r0 + rloc + r) * D + col] = fmaxf(acc2[m][r] + bv, 0.0f);
            }
        }
    }
}

// ---------------------------------------------------------------- two-stage pooling
#define PROWS 1024
__global__ __launch_bounds__(256) void k_pool2(const float* __restrict__ X,
                                               const int* __restrict__ bidx,
                                               float* __restrict__ PL) {
    __shared__ float lds[NG * D];
    int tid = threadIdx.x;
    for (int i = tid; i < NG * D; i += 256) lds[i] = 0.0f;
    __syncthreads();
    int base = blockIdx.x * PROWS;
    int f = tid & 63, rg = tid >> 6;
    for (int r = base + rg; r < base + PROWS; r += 4) {
        int g = bidx[r];
        atomicAdd(&lds[g * D + f], X[(size_t)r * D + f]);
    }
    __syncthreads();
    for (int i = tid; i < NG * D; i += 256) {
        float v = lds[i];
        if (v != 0.0f) fatomic_add(&PL[i], v);
    }
}

// ---------------------------------------------------------------- final linear head
__global__ void k_final(const float* __restrict__ pooled, const float* __restrict__ lin_w,
                        const float* __restrict__ lin_b, float* __restrict__ out) {
    int g = threadIdx.x;
    if (g >= NG) return;
    float acc = lin_b[0];
#pragma unroll
    for (int d2 = 0; d2 < D; ++d2) acc += pooled[g * D + d2] * lin_w[d2];
    out[g] = fmaxf(acc, 0.0f);
}

// ---------------------------------------------------------------- launch
extern "C" void kernel_launch(void* const* d_in, const int* in_sizes, int n_in,
                              void* d_out, int out_size, void* d_ws, size_t ws_size,
                              hipStream_t stream) {
    const float* x0    = (const float*)d_in[0];
    const float* stat  = (const float*)d_in[1];
    const float* W1    = (const float*)d_in[2];
    const float* b1    = (const float*)d_in[3];
    const float* W2    = (const float*)d_in[4];
    const float* b2    = (const float*)d_in[5];
    const float* W3    = (const float*)d_in[6];
    const float* b3    = (const float*)d_in[7];
    const float* eps   = (const float*)d_in[8];
    const float* lin_w = (const float*)d_in[9];
    const float* lin_b = (const float*)d_in[10];
    const int* inner_src = (const int*)d_in[11];
    const int* inner_dst = (const int*)d_in[12];
    const int* fwd_src   = (const int*)d_in[13];
    const int* fwd_dst   = (const int*)d_in[14];
    const int* bwd_src   = (const int*)d_in[15];
    const int* bwd_dst   = (const int*)d_in[16];
    const int* bidx      = (const int*)d_in[17];

    float* X  = (float*)d_ws;                                 // NND*64 f32
    float* PL = X + (size_t)NND * D;                          // NG*64 f32
    _Float16* Th  = (_Float16*)(PL + NG * D);                 // [P][96]
    _Float16* H1p = Th + (size_t)P * KP1;                     // [P][256]
    _Float16* w1p = H1p + (size_t)P * H;                      // [4][256][96]
    _Float16* w2p = w1p + (size_t)4 * H * KP1;                // [4][256][256]
    _Float16* w3p = w2p + (size_t)4 * H * H;                  // [4][64][256]
    int* deg      = (int*)(w3p + (size_t)4 * D * H);          // NSETS*P
    int* rowstart = deg + (size_t)NSETS * P;                  // NSETS*RSP
    int* rank     = rowstart + (size_t)NSETS * RSP;           // NSETS*EDG
    int* elist    = rank + (size_t)NSETS * EDG;               // NSETS*EDG

    // ---- init X + zero deg/PL
    {
        int tot = NND * D + NSETS * P + NG * D;
        k_init_x<<<(tot + 255) / 256, 256, 0, stream>>>(x0, X, deg, PL);
    }
    // ---- weight prep (single fp16)
    {
        int tot = 4 * H * KP1 + 4 * H * H + 4 * D * H;
        k_wconv_all<<<(tot + 255) / 256, 256, 0, stream>>>(W1, W2, W3, w1p, w2p, w3p);
    }
    // ---- CSR build (R15-proven 3-kernel pipeline)
    k_csr_hist<<<(NSETS * EDG) / 256, 256, 0, stream>>>(inner_dst, fwd_dst, bwd_dst, deg, rank);
    k_csr_scan<<<NSETS, 1024, 0, stream>>>(deg, rowstart);
    k_csr_scatter<<<(NSETS * EDG) / 256, 256, 0, stream>>>(inner_src, inner_dst, fwd_src, fwd_dst,
                                                           bwd_src, bwd_dst, rowstart, rank, elist);

    _Float16* w13p = w1p + (size_t)3 * H * KP1;
    const float* b13 = b1 + 3 * H;

    auto conv_plain = [&](int set, int gbase_out) {
        k_mlp123<0><<<P / 64, 512, 0, stream>>>(
            Th,
            w1p + (size_t)set * H * KP1, b1 + set * H,
            w2p + (size_t)set * H * H, b2 + set * H,
            w3p + (size_t)set * D * H, b3 + set * D,
            X + (size_t)gbase_out * D,
            nullptr, nullptr, nullptr, 0, nullptr);
    };
    auto conv_fused = [&](int set, int gbase_node) {   // X stays in LDS; phase4 -> global H1
        k_mlp123<1><<<P / 64, 512, 0, stream>>>(
            Th,
            w1p + (size_t)set * H * KP1, b1 + set * H,
            w2p + (size_t)set * H * H, b2 + set * H,
            w3p + (size_t)set * D * H, b3 + set * D,
            nullptr,
            w13p, b13, H1p, gbase_node, stat);
    };
    auto node_dnn = [&](int gbase_out) {
        k_mlp23<<<P / 64, 512, 0, stream>>>(
            H1p,
            w2p + (size_t)3 * H * H, b2 + 3 * H,
            w3p + (size_t)3 * D * H, b3 + 3 * D,
            X + (size_t)gbase_out * D);
    };
    auto gather = [&](int t, int dst_gbase, int src_gbase, int ei) {
        k_gather_T<<<P / 4, 256, 0, stream>>>(
            X, stat, elist + (size_t)t * EDG, rowstart + (size_t)t * RSP,
            Th, dst_gbase, src_gbase, eps, ei);
    };

    // forward pass
    for (int il = 0; il < NLAYERS; ++il) {
        int s0 = il * P;
        gather(il, s0, s0, 0);
        conv_plain(0, s0);
        if (il == NLAYERS - 1) continue;
        gather(5 + il, s0 + P, s0, 1);
        conv_fused(1, s0 + P);
        node_dnn(s0 + P);
    }
    // backward pass
    for (int il = NLAYERS - 1; il >= 1; --il) {
        int s0 = (il - 1) * P;
        gather(9 + (il - 1), s0, s0 + P, 2);
        conv_plain(2, s0);
        gather(il - 1, s0, s0, 0);
        conv_fused(0, s0);
        node_dnn(s0);
    }

    k_pool2<<<NND / PROWS, 256, 0, stream>>>(X, bidx, PL);
    k_final<<<1, 64, 0, stream>>>(PL, lin_w, lin_b, (float*)d_out);
}

// Round 26
// 907.693 us; speedup vs baseline: 1.7839x; 1.0176x over previous
//
#include <hip/hip_runtime.h>

#define P 16384
#define NLAYERS 5
#define NND 98304          // P*(NLAYERS+1)
#define D 64
#define S 16
#define F 80               // D+S
#define KP1 96             // K of layer-1 GEMM padded to 32
#define H 256
#define EDG 262144         // 1<<18
#define NG 64
#define NSETS 13           // 5 inner + 4 fwd + 4 bwd
#define RSP 16385          // rowstart pitch (P+1)
#define LDP 40             // LDS K-stride for 32-chunks (80B rows, <=2-way aliasing)
#define LH2 264            // H1s/H2s LDS row stride (256+8)
#define LXS 100            // X-tile LDS row stride (96+4)

typedef __attribute__((ext_vector_type(8))) _Float16 f16x8;
typedef __attribute__((ext_vector_type(4))) _Float16 f16x4;
typedef __attribute__((ext_vector_type(4))) float f32x4;

// ---------------------------------------------------------------- utilities
__device__ __forceinline__ void fatomic_add(float* p, float v) {
    unsafeAtomicAdd(p, v);
}

// ---------------------------------------------------------------- init X (+fp16 mirror) + zero deg + zero PL
__global__ void k_init_x(const float* __restrict__ x0, float* __restrict__ X,
                         _Float16* __restrict__ Xh,
                         int* __restrict__ deg, float* __restrict__ PL) {
    int idx = blockIdx.x * blockDim.x + threadIdx.x;
    if (idx < NND * D) {
        int row = idx >> 6, f = idx & 63;
        float v = (f == 0) ? x0[row] : 0.0f;
        X[idx] = v;
        Xh[idx] = (_Float16)v;
        return;
    }
    int r = idx - NND * D;
    if (r < NSETS * P) { deg[r] = 0; return; }
    r -= NSETS * P;
    if (r < NG * D) PL[r] = 0.0f;
}

// ---------------------------------------------------------------- weight transpose -> fp16 + static -> fp16
__global__ void k_wconv_all(const float* __restrict__ W1, const float* __restrict__ W2,
                            const float* __restrict__ W3, const float* __restrict__ stat,
                            _Float16* __restrict__ w1, _Float16* __restrict__ w2,
                            _Float16* __restrict__ w3, _Float16* __restrict__ st16) {
    const int n1 = 4 * H * KP1, n2 = 4 * H * H, n3 = 4 * D * H;
    int idx = blockIdx.x * blockDim.x + threadIdx.x;
    if (idx >= n1 + n2 + n3) {
        int i = idx - (n1 + n2 + n3);
        if (i < NND * S) st16[i] = (_Float16)stat[i];
        return;
    }
    const float* W; _Float16* h; int K, N, Kp, i;
    if (idx < n1)              { W = W1; h = w1; K = F; N = H; Kp = KP1; i = idx; }
    else if (idx < n1 + n2)    { W = W2; h = w2; K = H; N = H; Kp = H;   i = idx - n1; }
    else                       { W = W3; h = w3; K = H; N = D; Kp = H;  i = idx - n1 - n2; }
    int set = i / (N * Kp), rem = i - set * (N * Kp);
    int n = rem / Kp, kp = rem - n * Kp;
    float v = (kp < K) ? W[(size_t)set * K * N + (size_t)kp * N + n] : 0.0f;
    h[i] = (_Float16)v;
}

// ---------------------------------------------------------------- CSR build (batched, 13 sets) — R15-proven
__device__ __forceinline__ const int* set_ptr(int t, const int* inner, const int* fwd,
                                              const int* bwd) {
    if (t < 5) return inner + (size_t)t * EDG;
    if (t < 9) return fwd + (size_t)(t - 5) * EDG;
    return bwd + (size_t)(t - 9) * EDG;
}

__global__ void k_csr_hist(const int* __restrict__ inner_dst, const int* __restrict__ fwd_dst,
                           const int* __restrict__ bwd_dst, int* __restrict__ deg,
                           int* __restrict__ rank) {
    int idx = blockIdx.x * blockDim.x + threadIdx.x;
    if (idx >= NSETS * EDG) return;
    int t = idx >> 18, e = idx & (EDG - 1);
    const int* dstp = set_ptr(t, inner_dst, fwd_dst, bwd_dst);
    rank[idx] = atomicAdd(&deg[t * P + dstp[e]], 1);
}

__global__ __launch_bounds__(1024) void k_csr_scan(const int* __restrict__ deg,
                                                   int* __restrict__ rowstart) {
    __shared__ int part[1024];
    int t = blockIdx.x;
    const int* d = deg + t * P;
    int* rs = rowstart + (size_t)t * RSP;
    int tid = threadIdx.x;
    int base = tid * 16;
    int loc[16], sum = 0;
#pragma unroll
    for (int i = 0; i < 16; ++i) { loc[i] = sum; sum += d[base + i]; }
    part[tid] = sum;
    __syncthreads();
    for (int off = 1; off < 1024; off <<= 1) {
        int v = (tid >= off) ? part[tid - off] : 0;
        __syncthreads();
        part[tid] += v;
        __syncthreads();
    }
    int pre = tid ? part[tid - 1] : 0;
#pragma unroll
    for (int i = 0; i < 16; ++i) rs[base + i] = pre + loc[i];
    if (tid == 1023) rs[P] = pre + sum;
}

__global__ void k_csr_scatter(const int* __restrict__ inner_src, const int* __restrict__ inner_dst,
                              const int* __restrict__ fwd_src, const int* __restrict__ fwd_dst,
                              const int* __restrict__ bwd_src, const int* __restrict__ bwd_dst,
                              const int* __restrict__ rowstart, const int* __restrict__ rank,
                              int* __restrict__ elist) {
    int idx = blockIdx.x * blockDim.x + threadIdx.x;
    if (idx >= NSETS * EDG) return;
    int t = idx >> 18, e = idx & (EDG - 1);
    const int* srcp = set_ptr(t, inner_src, fwd_src, bwd_src);
    const int* dstp = set_ptr(t, inner_dst, fwd_dst, bwd_dst);
    int dv = dstp[e];
    elist[(size_t)t * EDG + rowstart[(size_t)t * RSP + dv] + rank[idx]] = srcp[e];
}

// ---------------------------------------------------------------- gather conv input (wave per node, 4-row ILP, fp16 reads)
// lane l: row-group rg=l>>4, chunk c=l&15. Neighbor rows read from fp16 mirror (2.5 lines/edge).
// Self term read fp32-exact. Output T fp16.
__global__ __launch_bounds__(256) void k_gather_T(const float* __restrict__ X,
                                                  const _Float16* __restrict__ Xh,
                                                  const _Float16* __restrict__ st16,
                                                  const int* __restrict__ elist,
                                                  const int* __restrict__ rowstart,
                                                  _Float16* __restrict__ Th,
                                                  int dst_gbase, int src_gbase,
                                                  const float* __restrict__ eps, int ei,
                                                  const float* __restrict__ stf) {
    int wv = threadIdx.x >> 6, l = threadIdx.x & 63;
    int v = blockIdx.x * 4 + wv;
    int beg = rowstart[v], end = rowstart[v + 1];
    float scale = 1.0f + eps[ei];
    int rg = l >> 4, c = l & 15;
    float ax0 = 0.f, ax1 = 0.f, ax2 = 0.f, ax3 = 0.f, as = 0.f;
    int i = beg;
    for (; i + 4 <= end; i += 4) {
        int s = src_gbase + elist[i + rg];
        f16x4 xv = *(const f16x4*)&Xh[(size_t)s * D + 4 * c];
        ax0 += (float)xv[0]; ax1 += (float)xv[1]; ax2 += (float)xv[2]; ax3 += (float)xv[3];
        as += (float)st16[(size_t)s * S + c];
    }
    if (i < end) {
        int rem = end - i;
        if (rg < rem) {
            int s = src_gbase + elist[i + rg];
            f16x4 xv = *(const f16x4*)&Xh[(size_t)s * D + 4 * c];
            ax0 += (float)xv[0]; ax1 += (float)xv[1]; ax2 += (float)xv[2]; ax3 += (float)xv[3];
            as += (float)st16[(size_t)s * S + c];
        }
    }
#pragma unroll
    for (int off = 16; off < 64; off <<= 1) {
        ax0 += __shfl_xor(ax0, off, 64);
        ax1 += __shfl_xor(ax1, off, 64);
        ax2 += __shfl_xor(ax2, off, 64);
        ax3 += __shfl_xor(ax3, off, 64);
        as  += __shfl_xor(as,  off, 64);
    }
    if (l < 16) {
        int g = dst_gbase + v;
        float4 sx = *(const float4*)&X[(size_t)g * D + 4 * l];
        f16x4 hv;
        hv[0] = (_Float16)(ax0 + scale * sx.x);
        hv[1] = (_Float16)(ax1 + scale * sx.y);
        hv[2] = (_Float16)(ax2 + scale * sx.z);
        hv[3] = (_Float16)(ax3 + scale * sx.w);
        *(f16x4*)&Th[(size_t)v * KP1 + 4 * l] = hv;
        Th[(size_t)v * KP1 + D + l] = (_Float16)(as + scale * stf[(size_t)g * S + l]);
        Th[(size_t)v * KP1 + F + l] = (_Float16)0.0f;   // pad cols 80..95
    }
}

// ---------------------------------------------------------------- fused conv MLP: T -> H1(LDS) -> H2(LDS) -> X
// 64-row tile, 8 waves, 1 block/CU. MODE 0: X(+Xh)->global. MODE 1: X in LDS; phase4 node GEMM1 -> global H1.
template<int MODE>
__global__ __launch_bounds__(512, 2) void k_mlp123(
    const _Float16* __restrict__ Tp,
    const _Float16* __restrict__ W1p, const float* __restrict__ b1,
    const _Float16* __restrict__ W2p, const float* __restrict__ b2,
    const _Float16* __restrict__ W3p, const float* __restrict__ b3,
    float* __restrict__ Xout, _Float16* __restrict__ Xhout,
    const _Float16* __restrict__ W1p3, const float* __restrict__ b13,
    _Float16* __restrict__ H1o,
    int st_gbase, const float* __restrict__ stsrc)
{
    __shared__ _Float16 A1h[64][LDP];                  // 5.1 KB (T k-chunk staging)
    __shared__ _Float16 B1h[256][LDP];                 // 20.5 KB (W1 / W2 / W3 / W1_3)
    __shared__ _Float16 H1s[64][LH2];                  // 33.8 KB
    __shared__ _Float16 H2hs[64][LH2];                 // 33.8 KB
    __shared__ _Float16 Xsh[(MODE == 1) ? 64 : 1][LXS];// 12.8 KB (MODE 1)

    int tid = threadIdx.x;
    int lane = tid & 63, wid = tid >> 6;
    int la = lane & 15, lg = lane >> 4;
    int r0 = blockIdx.x * 64;

    // ================= phase 0: H1s = relu(T @ W1^T + b1), 64x256, K=96
    {
        f32x4 acc0[4][2] = {};
        for (int k0 = 0; k0 < KP1; k0 += 32) {
            if (tid < 256) {
                int ar = tid >> 2, aq = (tid & 3) * 8;
                *(f16x8*)&A1h[ar][aq] = *(const f16x8*)&Tp[(size_t)(r0 + ar) * KP1 + k0 + aq];
            }
#pragma unroll
            for (int j = 0; j < 2; ++j) {
                int id = j * 512 + tid;
                int br = id >> 2, bq = (id & 3) * 8;
                *(f16x8*)&B1h[br][bq] = *(const f16x8*)&W1p[(size_t)br * KP1 + k0 + bq];
            }
            __syncthreads();

            int kf = lg * 8;
            f16x8 ah[4], bh[2];
#pragma unroll
            for (int m = 0; m < 4; ++m) ah[m] = *(const f16x8*)&A1h[m * 16 + la][kf];
#pragma unroll
            for (int n = 0; n < 2; ++n) bh[n] = *(const f16x8*)&B1h[wid * 32 + n * 16 + la][kf];
#pragma unroll
            for (int m = 0; m < 4; ++m)
#pragma unroll
                for (int n = 0; n < 2; ++n)
                    acc0[m][n] = __builtin_amdgcn_mfma_f32_16x16x32_f16(ah[m], bh[n], acc0[m][n], 0, 0, 0);
            __syncthreads();
        }
#pragma unroll
        for (int n = 0; n < 2; ++n) {
            int col = wid * 32 + n * 16 + la;
            float bv = b1[col];
#pragma unroll
            for (int m = 0; m < 4; ++m) {
                int row = m * 16 + lg * 4;
#pragma unroll
                for (int r = 0; r < 4; ++r) {
                    H1s[row + r][col] = (_Float16)fmaxf(acc0[m][n][r] + bv, 0.0f);
                }
            }
        }
        __syncthreads();
    }

    // ================= phase 1: H2 = relu(H1s @ W2^T + b2), 64x256, K=256
    f32x4 acc[4][2] = {};
    for (int k0 = 0; k0 < H; k0 += 32) {
#pragma unroll
        for (int j = 0; j < 2; ++j) {
            int id = j * 512 + tid;
            int br = id >> 2, bq = (id & 3) * 8;
            *(f16x8*)&B1h[br][bq] = *(const f16x8*)&W2p[(size_t)br * H + k0 + bq];
        }
        __syncthreads();

        int kf = lg * 8;
        f16x8 ah[4], bh[2];
#pragma unroll
        for (int m = 0; m < 4; ++m) ah[m] = *(const f16x8*)&H1s[m * 16 + la][k0 + kf];
#pragma unroll
        for (int n = 0; n < 2; ++n) bh[n] = *(const f16x8*)&B1h[wid * 32 + n * 16 + la][kf];
#pragma unroll
        for (int m = 0; m < 4; ++m)
#pragma unroll
            for (int n = 0; n < 2; ++n)
                acc[m][n] = __builtin_amdgcn_mfma_f32_16x16x32_f16(ah[m], bh[n], acc[m][n], 0, 0, 0);
        __syncthreads();
    }
#pragma unroll
    for (int n = 0; n < 2; ++n) {
        int col = wid * 32 + n * 16 + la;
        float bv = b2[col];
#pragma unroll
        for (int m = 0; m < 4; ++m) {
            int row = m * 16 + lg * 4;
#pragma unroll
            for (int r = 0; r < 4; ++r) {
                H2hs[row + r][col] = (_Float16)fmaxf(acc[m][n][r] + bv, 0.0f);
            }
        }
    }
    __syncthreads();

    // ================= phase 2: Xtile = relu(H2 @ W3^T + b3), K=256
    int wm = wid >> 2, wn = wid & 3;
    f32x4 acc2[2] = {};
    {
        for (int k0 = 0; k0 < H; k0 += 32) {
            if (tid < 256) {
                int br = tid >> 2, bq = (tid & 3) * 8;
                *(f16x8*)&B1h[br][bq] = *(const f16x8*)&W3p[(size_t)br * H + k0 + bq];
            }
            __syncthreads();

            int kf = lg * 8;
            f16x8 ah[2], bh;
#pragma unroll
            for (int m = 0; m < 2; ++m) ah[m] = *(const f16x8*)&H2hs[wm * 32 + m * 16 + la][k0 + kf];
            bh = *(const f16x8*)&B1h[wn * 16 + la][kf];
#pragma unroll
            for (int m = 0; m < 2; ++m)
                acc2[m] = __builtin_amdgcn_mfma_f32_16x16x32_f16(ah[m], bh, acc2[m], 0, 0, 0);
            __syncthreads();
        }
    }
    {
        int col = wn * 16 + la;
        float bv = b3[col];
#pragma unroll
        for (int m = 0; m < 2; ++m) {
            int rloc = wm * 32 + m * 16 + lg * 4;
#pragma unroll
            for (int r = 0; r < 4; ++r) {
                float v = fmaxf(acc2[m][r] + bv, 0.0f);
                if (MODE == 0) {
                    size_t o = (size_t)(r0 + rloc + r) * D + col;
                    Xout[o] = v;
                    Xhout[o] = (_Float16)v;
                } else {
                    Xsh[rloc + r][col] = (_Float16)v;
                }
            }
        }
    }

    if (MODE == 1) {
        {   // static cols 64..79 + zero pad 80..95
            int row = tid >> 3, c2 = (tid & 7) * 2;
            int g = st_gbase + r0 + row;
            float2 sv = *(const float2*)&stsrc[(size_t)g * S + c2];
            Xsh[row][D + c2] = (_Float16)sv.x;
            Xsh[row][D + c2 + 1] = (_Float16)sv.y;
            Xsh[row][F + c2] = (_Float16)0.0f;
            Xsh[row][F + c2 + 1] = (_Float16)0.0f;
        }
        __syncthreads();

        // phase 4: H1' = relu([X|st|0] @ W1_3^T + b1_3), 64x256, K=96
        f32x4 acc4[4][2] = {};
        for (int k0 = 0; k0 < KP1; k0 += 32) {
#pragma unroll
            for (int j = 0; j < 2; ++j) {
                int id = j * 512 + tid;
                int br = id >> 2, bq = (id & 3) * 8;
                *(f16x8*)&B1h[br][bq] = *(const f16x8*)&W1p3[(size_t)br * KP1 + k0 + bq];
            }
            __syncthreads();

            int kf = lg * 8;
            f16x8 ah[4], bh[2];
#pragma unroll
            for (int m = 0; m < 4; ++m) ah[m] = *(const f16x8*)&Xsh[m * 16 + la][k0 + kf];
#pragma unroll
            for (int n = 0; n < 2; ++n) bh[n] = *(const f16x8*)&B1h[wid * 32 + n * 16 + la][kf];
#pragma unroll
            for (int m = 0; m < 4; ++m)
#pragma unroll
                for (int n = 0; n < 2; ++n)
                    acc4[m][n] = __builtin_amdgcn_mfma_f32_16x16x32_f16(ah[m], bh[n], acc4[m][n], 0, 0, 0);
            __syncthreads();
        }
#pragma unroll
        for (int n = 0; n < 2; ++n) {
            int col = wid * 32 + n * 16 + la;
            float bv = b13[col];
#pragma unroll
            for (int m = 0; m < 4; ++m) {
                int row = r0 + m * 16 + lg * 4;
#pragma unroll
                for (int r = 0; r < 4; ++r) {
                    H1o[(size_t)(row + r) * H + col] = (_Float16)fmaxf(acc4[m][n][r] + bv, 0.0f);
                }
            }
        }
    }
}

// ---------------------------------------------------------------- node_dnn GEMM2+GEMM3 (reads global H1) — writes X + Xh
__global__ __launch_bounds__(512, 4) void k_mlp23(
    const _Float16* __restrict__ H1p,
    const _Float16* __restrict__ W2p, const float* __restrict__ b2,
    const _Float16* __restrict__ W3p, const float* __restrict__ b3,
    float* __restrict__ Xout, _Float16* __restrict__ Xhout)
{
    __shared__ _Float16 A1h[64][LDP];
    __shared__ _Float16 B1h[256][LDP];
    __shared__ _Float16 H2hs[64][LH2];

    int tid = threadIdx.x;
    int lane = tid & 63, wid = tid >> 6;
    int la = lane & 15, lg = lane >> 4;
    int r0 = blockIdx.x * 64;

    // phase 1: H2 = relu(H1 @ W2^T + b2)
    f32x4 acc[4][2] = {};
    for (int k0 = 0; k0 < H; k0 += 32) {
        if (tid < 256) {
            int ar = tid >> 2, aq = (tid & 3) * 8;
            *(f16x8*)&A1h[ar][aq] = *(const f16x8*)&H1p[(size_t)(r0 + ar) * H + k0 + aq];
        }
#pragma unroll
        for (int j = 0; j < 2; ++j) {
            int id = j * 512 + tid;
            int br = id >> 2, bq = (id & 3) * 8;
            *(f16x8*)&B1h[br][bq] = *(const f16x8*)&W2p[(size_t)br * H + k0 + bq];
        }
        __syncthreads();

        int kf = lg * 8;
        f16x8 ah[4], bh[2];
#pragma unroll
        for (int m = 0; m < 4; ++m) ah[m] = *(const f16x8*)&A1h[m * 16 + la][kf];
#pragma unroll
        for (int n = 0; n < 2; ++n) bh[n] = *(const f16x8*)&B1h[wid * 32 + n * 16 + la][kf];
#pragma unroll
        for (int m = 0; m < 4; ++m)
#pragma unroll
            for (int n = 0; n < 2; ++n)
                acc[m][n] = __builtin_amdgcn_mfma_f32_16x16x32_f16(ah[m], bh[n], acc[m][n], 0, 0, 0);
        __syncthreads();
    }
#pragma unroll
    for (int n = 0; n < 2; ++n) {
        int col = wid * 32 + n * 16 + la;
        float bv = b2[col];
#pragma unroll
        for (int m = 0; m < 4; ++m) {
            int row = m * 16 + lg * 4;
#pragma unroll
            for (int r = 0; r < 4; ++r) {
                H2hs[row + r][col] = (_Float16)fmaxf(acc[m][n][r] + bv, 0.0f);
            }
        }
    }
    __syncthreads();

    // phase 2: X = relu(H2 @ W3^T + b3)
    int wm = wid >> 2, wn = wid & 3;
    f32x4 acc2[2] = {};
    for (int k0 = 0; k0 < H; k0 += 32) {
        if (tid < 256) {
            int br = tid >> 2, bq = (tid & 3) * 8;
            *(f16x8*)&B1h[br][bq] = *(const f16x8*)&W3p[(size_t)br * H + k0 + bq];
        }
        __syncthreads();

        int kf = lg * 8;
        f16x8 ah[2], bh;
#pragma unroll
        for (int m = 0; m < 2; ++m) ah[m] = *(const f16x8*)&H2hs[wm * 32 + m * 16 + la][k0 + kf];
        bh = *(const f16x8*)&B1h[wn * 16 + la][kf];
#pragma unroll
        for (int m = 0; m < 2; ++m)
            acc2[m] = __builtin_amdgcn_mfma_f32_16x16x32_f16(ah[m], bh, acc2[m], 0, 0, 0);
        __syncthreads();
    }
    {
        int col = wn * 16 + la;
        float bv = b3[col];
#pragma unroll
        for (int m = 0; m < 2; ++m) {
            int rloc = wm * 32 + m * 16 + lg * 4;
#pragma unroll
            for (int r = 0; r < 4; ++r) {
                float v = fmaxf(acc2[m][r] + bv, 0.0f);
                size_t o = (size_t)(r0 + rloc + r) * D + col;
                Xout[o] = v;
                Xhout[o] = (_Float16)v;
            }
        }
    }
}

// ---------------------------------------------------------------- two-stage pooling
#define PROWS 1024
__global__ __launch_bounds__(256) void k_pool2(const float* __restrict__ X,
                                               const int* __restrict__ bidx,
                                               float* __restrict__ PL) {
    __shared__ float lds[NG * D];
    int tid = threadIdx.x;
    for (int i = tid; i < NG * D; i += 256) lds[i] = 0.0f;
    __syncthreads();
    int base = blockIdx.x * PROWS;
    int f = tid & 63, rg = tid >> 6;
    for (int r = base + rg; r < base + PROWS; r += 4) {
        int g = bidx[r];
        atomicAdd(&lds[g * D + f], X[(size_t)r * D + f]);
    }
    __syncthreads();
    for (int i = tid; i < NG * D; i += 256) {
        float v = lds[i];
        if (v != 0.0f) fatomic_add(&PL[i], v);
    }
}

// ---------------------------------------------------------------- final linear head
__global__ void k_final(const float* __restrict__ pooled, const float* __restrict__ lin_w,
                        const float* __restrict__ lin_b, float* __restrict__ out) {
    int g = threadIdx.x;
    if (g >= NG) return;
    float acc = lin_b[0];
#pragma unroll
    for (int d2 = 0; d2 < D; ++d2) acc += pooled[g * D + d2] * lin_w[d2];
    out[g] = fmaxf(acc, 0.0f);
}

// ---------------------------------------------------------------- launch
extern "C" void kernel_launch(void* const* d_in, const int* in_sizes, int n_in,
                              void* d_out, int out_size, void* d_ws, size_t ws_size,
                              hipStream_t stream) {
    const float* x0    = (const float*)d_in[0];
    const float* stat  = (const float*)d_in[1];
    const float* W1    = (const float*)d_in[2];
    const float* b1    = (const float*)d_in[3];
    const float* W2    = (const float*)d_in[4];
    const float* b2    = (const float*)d_in[5];
    const float* W3    = (const float*)d_in[6];
    const float* b3    = (const float*)d_in[7];
    const float* eps   = (const float*)d_in[8];
    const float* lin_w = (const float*)d_in[9];
    const float* lin_b = (const float*)d_in[10];
    const int* inner_src = (const int*)d_in[11];
    const int* inner_dst = (const int*)d_in[12];
    const int* fwd_src   = (const int*)d_in[13];
    const int* fwd_dst   = (const int*)d_in[14];
    const int* bwd_src   = (const int*)d_in[15];
    const int* bwd_dst   = (const int*)d_in[16];
    const int* bidx      = (const int*)d_in[17];

    float* X  = (float*)d_ws;                                 // NND*64 f32
    float* PL = X + (size_t)NND * D;                          // NG*64 f32
    _Float16* Xh  = (_Float16*)(PL + NG * D);                 // [NND][64] fp16 mirror
    _Float16* st16 = Xh + (size_t)NND * D;                    // [NND][16] fp16 static
    _Float16* Th  = st16 + (size_t)NND * S;                   // [P][96]
    _Float16* H1p = Th + (size_t)P * KP1;                     // [P][256]
    _Float16* w1p = H1p + (size_t)P * H;                      // [4][256][96]
    _Float16* w2p = w1p + (size_t)4 * H * KP1;                // [4][256][256]
    _Float16* w3p = w2p + (size_t)4 * H * H;                  // [4][64][256]
    int* deg      = (int*)(w3p + (size_t)4 * D * H);          // NSETS*P
    int* rowstart = deg + (size_t)NSETS * P;                  // NSETS*RSP
    int* rank     = rowstart + (size_t)NSETS * RSP;           // NSETS*EDG
    int* elist    = rank + (size_t)NSETS * EDG;               // NSETS*EDG

    // ---- init X/Xh + zero deg/PL
    {
        int tot = NND * D + NSETS * P + NG * D;
        k_init_x<<<(tot + 255) / 256, 256, 0, stream>>>(x0, X, Xh, deg, PL);
    }
    // ---- weight prep (single fp16) + static fp16
    {
        int tot = 4 * H * KP1 + 4 * H * H + 4 * D * H + NND * S;
        k_wconv_all<<<(tot + 255) / 256, 256, 0, stream>>>(W1, W2, W3, stat, w1p, w2p, w3p, st16);
    }
    // ---- CSR build (R15-proven 3-kernel pipeline)
    k_csr_hist<<<(NSETS * EDG) / 256, 256, 0, stream>>>(inner_dst, fwd_dst, bwd_dst, deg, rank);
    k_csr_scan<<<NSETS, 1024, 0, stream>>>(deg, rowstart);
    k_csr_scatter<<<(NSETS * EDG) / 256, 256, 0, stream>>>(inner_src, inner_dst, fwd_src, fwd_dst,
                                                           bwd_src, bwd_dst, rowstart, rank, elist);

    _Float16* w13p = w1p + (size_t)3 * H * KP1;
    const float* b13 = b1 + 3 * H;

    auto conv_plain = [&](int set, int gbase_out) {
        k_mlp123<0><<<P / 64, 512, 0, stream>>>(
            Th,
            w1p + (size_t)set * H * KP1, b1 + set * H,
            w2p + (size_t)set * H * H, b2 + set * H,
            w3p + (size_t)set * D * H, b3 + set * D,
            X + (size_t)gbase_out * D, Xh + (size_t)gbase_out * D,
            nullptr, nullptr, nullptr, 0, nullptr);
    };
    auto conv_fused = [&](int set, int gbase_node) {
        k_mlp123<1><<<P / 64, 512, 0, stream>>>(
            Th,
            w1p + (size_t)set * H * KP1, b1 + set * H,
            w2p + (size_t)set * H * H, b2 + set * H,
            w3p + (size_t)set * D * H, b3 + set * D,
            nullptr, nullptr,
            w13p, b13, H1p, gbase_node, stat);
    };
    auto node_dnn = [&](int gbase_out) {
        k_mlp23<<<P / 64, 512, 0, stream>>>(
            H1p,
            w2p + (size_t)3 * H * H, b2 + 3 * H,
            w3p + (size_t)3 * D * H, b3 + 3 * D,
            X + (size_t)gbase_out * D, Xh + (size_t)gbase_out * D);
    };
    auto gather = [&](int t, int dst_gbase, int src_gbase, int ei) {
        k_gather_T<<<P / 4, 256, 0, stream>>>(
            X, Xh, st16, elist + (size_t)t * EDG, rowstart + (size_t)t * RSP,
            Th, dst_gbase, src_gbase, eps, ei, stat);
    };

    // forward pass
    for (int il = 0; il < NLAYERS; ++il) {
        int s0 = il * P;
        gather(il, s0, s0, 0);
        conv_plain(0, s0);
        if (il == NLAYERS - 1) continue;
        gather(5 + il, s0 + P, s0, 1);
        conv_fused(1, s0 + P);
        node_dnn(s0 + P);
    }
    // backward pass
    for (int il = NLAYERS - 1; il >= 1; --il) {
        int s0 = (il - 1) * P;
        gather(9 + (il - 1), s0, s0 + P, 2);
        conv_plain(2, s0);
        gather(il - 1, s0, s0, 0);
        conv_fused(0, s0);
        node_dnn(s0);
    }

    k_pool2<<<NND / PROWS, 256, 0, stream>>>(X, bidx, PL);
    k_final<<<1, 64, 0, stream>>>(PL, lin_w, lin_b, (float*)d_out);
}